// Round 12
// baseline (705.827 us; speedup 1.0000x reference)
//
#include <hip/hip_runtime.h>

// BasicBlock: y = relu(bn2(conv2(relu(bn1(conv1(x, we1))), we2)) + x)
// we{1,2} = sum_e alpha[e]*w{1,2}[e].
//
// R12: fused conv1+conv2 (R10's verified arithmetic) with register-pressure
// surgery. R10 was CORRECT (absmax .125) but spilled (790MB scratch writes).
// Change: conv1 runs 3 sequential Mfrags/wave, each with a single acc[4]
// (16 VGPR) and immediate bn1+relu+y1-LDS write, instead of acc1[3][4]=48
// held across the whole phase. conv2 (acc[4][2]) unchanged. Peak live set
// ~100 VGPR < 128. Traffic: xpad ~67MB read + out 103MB write; no y1pad,
// no fp32 x read. Two-pass floor was ~535MB -> fused ~330MB incl transform.
//
// xpad: NHWC bf16, 1px padded, chunk-swizzled (slot = c8 ^ ((2h+w)&7) in
// each 128B pixel) -> conflict-free stride-128 ds_read_b128 + verbatim
// window staging via linear global_load_lds with on-read decode.

typedef __bf16 bf16x8 __attribute__((ext_vector_type(8)));
typedef float f32x4 __attribute__((ext_vector_type(4)));
typedef unsigned short u16;
typedef u16 u16x8 __attribute__((ext_vector_type(8)));

#define NH 112
#define NW 112
#define PH 114
#define PW 114
#define INB 30720    // input window: 12 rows * 20 px * 128 B
#define Y1OFF 30720  // y1 tile: 10 * 18 * 128 = 23040 B

#define WAITVM(n) asm volatile("s_waitcnt vmcnt(" #n ")" ::: "memory")
#define WAITLG asm volatile("s_waitcnt lgkmcnt(0)" ::: "memory")
#define SCHEDB __builtin_amdgcn_sched_barrier(0)

__device__ __forceinline__ u16 f2b(float f) {
  unsigned u = __builtin_bit_cast(unsigned, f);
  u += 0x7FFFu + ((u >> 16) & 1u);
  return (u16)(u >> 16);
}
__device__ __forceinline__ float b2f(u16 b) {
  unsigned u = ((unsigned)b) << 16;
  return __builtin_bit_cast(float, u);
}

__device__ __forceinline__ void gl_lds16(const void* g, void* l) {
  __builtin_amdgcn_global_load_lds(
      (const __attribute__((address_space(1))) unsigned int*)g,
      (__attribute__((address_space(3))) unsigned int*)l, 16, 0, 0);
}

// ---------------------------------------------------------------------------
// zero the 1-px border ring of xpad
__global__ void border_zero(u16* __restrict__ a) {
  int idx = blockIdx.x * 256 + threadIdx.x;  // 32*452*8 = 115712 chunks
  if (idx >= 115712) return;
  int c8 = idx & 7;
  int t = idx >> 3;
  int img = t / 452, e = t % 452;
  int h, w;
  if (e < 114) { h = 0; w = e; }
  else if (e < 228) { h = 113; w = e - 114; }
  else if (e < 340) { h = e - 227; w = 0; }
  else { h = e - 339; w = 113; }
  u16x8 z = {0, 0, 0, 0, 0, 0, 0, 0};
  *reinterpret_cast<u16x8*>(a + (((long)img * PH + h) * PW + w) * 64 + c8 * 8) = z;
}

// ---------------------------------------------------------------------------
// x NCHW fp32 -> x_pad NHWC bf16 (1-px padded + chunk-swizzled). block=(b,h).
__global__ __launch_bounds__(256) void transform_kernel(const float* __restrict__ x,
                                                        u16* __restrict__ xpad) {
  __shared__ alignas(16) u16 t[7168];  // [112 px][64 ch], xor-swizzled bytes
  int tid = threadIdx.x, bid = blockIdx.x;
  int b = bid / NH, h = bid % NH;
  const float* src = x + (long)b * 64 * 12544 + h * NW;
  f32x4 v[7];
#pragma unroll
  for (int it = 0; it < 7; ++it) {
    int fid = it * 256 + tid;  // 1792 = 64 ch * 28 quads
    int c = fid / 28, wq = fid % 28;
    v[it] = *reinterpret_cast<const f32x4*>(src + c * 12544 + wq * 4);
  }
#pragma unroll
  for (int it = 0; it < 7; ++it) {
    int fid = it * 256 + tid;
    int c = fid / 28, wq = fid % 28;
    int key = (wq & 7) << 4;
#pragma unroll
    for (int j = 0; j < 4; ++j) {
      int px = wq * 4 + j;
      *reinterpret_cast<u16*>((char*)t + px * 128 + ((c * 2) ^ key)) = f2b(v[it][j]);
    }
  }
  __syncthreads();
  int hp = h + 1;
  u16* rowb = xpad + (((long)b * PH + hp) * PW) * 64;
#pragma unroll
  for (int it = 0; it < 4; ++it) {
    int cidx = it * 256 + tid;
    if (cidx < 896) {  // 112 px * 8 chunks
      int c8 = cidx & 7, px = cidx >> 3;
      int lchunk = c8 ^ ((px >> 2) & 7);
      u16x8 vv = *reinterpret_cast<const u16x8*>((const char*)t + px * 128 + lchunk * 16);
      int wp = px + 1;
      int gkey = (2 * hp + wp) & 7;
      *reinterpret_cast<u16x8*>(rowb + (long)wp * 64 + ((c8 ^ gkey) * 8)) = vv;
    }
  }
}

// ---------------------------------------------------------------------------
// fold experts -> w_eff bf16 [kpos][o][i] + folded BN constants
__global__ void prep_kernel(
    const float* __restrict__ w1, const float* __restrict__ w2,
    const float* __restrict__ alpha,
    const float* __restrict__ g1, const float* __restrict__ b1,
    const float* __restrict__ m1, const float* __restrict__ v1,
    const float* __restrict__ g2, const float* __restrict__ b2,
    const float* __restrict__ m2, const float* __restrict__ v2,
    u16* __restrict__ weff1, u16* __restrict__ weff2, float* __restrict__ bnc) {
  int idx = blockIdx.x * 256 + threadIdx.x;  // 36864
  if (idx < 36864) {
    int i = idx & 63;
    int o = (idx >> 6) & 63;
    int kpos = idx >> 12;
    int base = (o * 64 + i) * 9 + kpos;  // src [E][O][I][3][3]
    float a1 = 0.f, a2 = 0.f;
#pragma unroll
    for (int e = 0; e < 10; ++e) {
      float al = alpha[e];
      a1 += al * w1[e * 36864 + base];
      a2 += al * w2[e * 36864 + base];
    }
    weff1[idx] = f2b(a1);
    weff2[idx] = f2b(a2);
  }
  if (blockIdx.x == 0 && threadIdx.x < 64) {
    int c = threadIdx.x;
    float i1 = g1[c] * rsqrtf(v1[c] + 1e-5f);
    float i2 = g2[c] * rsqrtf(v2[c] + 1e-5f);
    bnc[c] = i1;
    bnc[64 + c] = b1[c] - m1[c] * i1;
    bnc[128 + c] = i2;
    bnc[192 + c] = b2[c] - m2[c] * i2;
  }
}

// ---------------------------------------------------------------------------
// fused conv1+conv2. 8x16 out px x 64 oc per tile, TILES tiles/block,
// 256 threads (4 waves). grid 1568 (= 8*196, XCD-bijective).
// LDS: [input 12x20x128 = 30720][y1 10x18x128 = 23040] = 53760 -> 2 blk/CU.
// ---------------------------------------------------------------------------
template <int TILES>
__global__ __launch_bounds__(256, 2) void fused_kernel(
    const u16* __restrict__ xpad, const u16* __restrict__ weff1,
    const u16* __restrict__ weff2, const float* __restrict__ bnc,
    float* __restrict__ out) {
  __shared__ alignas(1024) char smem[INB + 23040];

  const int tid = threadIdx.x, lane = tid & 63, wv = tid >> 6;
  const int ol = lane & 15, kg = (lane >> 4) & 3;
  const int f0 = (wv >> 1) * 4;  // conv2: wave's first out row
  const int nf0 = (wv & 1) * 2;  // conv2: wave's first oc fragment

  // BN constants
  float inv1[4], bias1[4], inv2[2], bias2[2];
#pragma unroll
  for (int nf = 0; nf < 4; ++nf) {
    int o = nf * 16 + ol;
    inv1[nf] = bnc[o];
    bias1[nf] = bnc[64 + o];
  }
#pragma unroll
  for (int j = 0; j < 2; ++j) {
    int o = (nf0 + j) * 16 + ol;
    inv2[j] = bnc[128 + o];
    bias2[j] = bnc[192 + o];
  }

  // tile decode (XCD-chunked bijective: 1568 = 8*196)
  int sb = (blockIdx.x & 7) * 196 + (blockIdx.x >> 3);
  int tb[TILES], th0[TILES], tw0[TILES];
#pragma unroll
  for (int t = 0; t < TILES; ++t) {
    int tt = sb * TILES + t;
    tb[t] = tt / 98;
    int r = tt % 98;
    th0[t] = (r / 7) * 8;
    tw0[t] = (r % 7) * 16;
  }

#pragma unroll
  for (int t = 0; t < TILES; ++t) {
    // ---- stage 12x20 window (1920 chunks, 30 glds wave-insts; clamped) ----
    const u16* xb = xpad + (long)tb[t] * (PH * PW * 64);
#pragma unroll
    for (int k = 0; k < 8; ++k) {
      int i = wv + k * 4;
      if (i < 30) {
        int cb = i * 64 + lane;  // chunk 0..1919
        int c8 = cb & 7, pc = cb >> 3;
        int r = pc / 20, c = pc % 20;
        int gh = th0[t] - 1 + r, gw = tw0[t] - 1 + c;
        int ghc = min(max(gh, 0), 113), gwc = min(max(gw, 0), 113);
        gl_lds16((const char*)(xb + ((long)(ghc * PW + gwc)) * 64) + c8 * 16,
                 smem + cb * 16);
      }
    }
    WAITVM(0);
    SCHEDB;
    // zero-fix chunks outside the padded buffer (2nd halo ring)
#pragma unroll
    for (int k = 0; k < 8; ++k) {
      int i = wv + k * 4;
      if (i < 30) {
        int cb = i * 64 + lane;
        int pc = cb >> 3;
        int r = pc / 20, c = pc % 20;
        int gh = th0[t] - 1 + r, gw = tw0[t] - 1 + c;
        if (!((unsigned)gh < 114u && (unsigned)gw < 114u))
          *reinterpret_cast<u16x8*>(smem + cb * 16) = u16x8{0, 0, 0, 0, 0, 0, 0, 0};
      }
    }
    WAITLG;
    SCHEDB;
    __builtin_amdgcn_s_barrier();
    SCHEDB;

    // ---- conv1: 3 SEQUENTIAL Mfrags per wave (acc[4] = 16 VGPR each),
    //      each followed immediately by bn1+relu -> y1 LDS write ----
#pragma unroll
    for (int lf = 0; lf < 3; ++lf) {
      const int fq = wv * 3 + lf;       // frag 0..11 over y1's 10x18 px
      const int ia = fq * 16 + ol;      // this lane's A-row pixel (may be >=180)
      const int rA = ia / 18, cA = ia % 18;

      f32x4 acc[4];
#pragma unroll
      for (int nf = 0; nf < 4; ++nf) acc[nf] = f32x4{0.f, 0.f, 0.f, 0.f};

#pragma unroll
      for (int kh = 0; kh < 3; ++kh)
#pragma unroll
        for (int kw = 0; kw < 3; ++kw) {
          int kpos = kh * 3 + kw;
#pragma unroll
          for (int ks = 0; ks < 2; ++ks) {
            int row = rA + kh, col = cA + kw;
            int slot = ((ks << 2) | kg) ^ ((2 * row + col + 5) & 7);
            bf16x8 a = *reinterpret_cast<const bf16x8*>(
                smem + (row * 20 + col) * 128 + slot * 16);
#pragma unroll
            for (int nf = 0; nf < 4; ++nf) {
              bf16x8 bw = __builtin_bit_cast(
                  bf16x8, *reinterpret_cast<const u16x8*>(
                              weff1 + ((kpos * 64 + nf * 16 + ol) * 64 + ks * 32 +
                                       kg * 8)));
              acc[nf] = __builtin_amdgcn_mfma_f32_16x16x32_bf16(a, bw, acc[nf], 0, 0, 0);
            }
          }
        }

      // bn1+relu -> y1 (bf16, swizzled; zero outside image = conv2 padding)
      char* y1 = smem + Y1OFF;
#pragma unroll
      for (int rg = 0; rg < 4; ++rg) {
        int p = fq * 16 + kg * 4 + rg;  // lane's D-row pixel
        if (p < 180) {
          int r = p / 18, c = p % 18;
          int gh1 = th0[t] - 1 + r, gw1 = tw0[t] - 1 + c;
          bool vld = (unsigned)gh1 < 112u && (unsigned)gw1 < 112u;
          int key = (2 * r + c) & 7;
          char* pb = y1 + (r * 18 + c) * 128;
#pragma unroll
          for (int nf = 0; nf < 4; ++nf) {
            int oc = nf * 16 + ol;
            float v = fmaxf(acc[nf][rg] * inv1[nf] + bias1[nf], 0.f);
            u16 bv = vld ? f2b(v) : (u16)0;
            *reinterpret_cast<u16*>(pb + (((oc >> 3) ^ key) * 16 + (oc & 7) * 2)) = bv;
          }
        }
      }
    }
    WAITLG;
    SCHEDB;
    __builtin_amdgcn_s_barrier();
    SCHEDB;

    // ---- conv2: 8x16 out px, wave = rows f0..f0+3 x oc frags nf0..nf0+1 ----
    f32x4 acc2[4][2];
#pragma unroll
    for (int mf = 0; mf < 4; ++mf)
#pragma unroll
      for (int j = 0; j < 2; ++j) acc2[mf][j] = f32x4{0.f, 0.f, 0.f, 0.f};

#pragma unroll
    for (int kw = 0; kw < 3; ++kw)
#pragma unroll
      for (int ks = 0; ks < 2; ++ks) {
        bf16x8 a[6];
#pragma unroll
        for (int u = 0; u < 6; ++u) {
          int rr = f0 + u, col = ol + kw;
          int slot = ((ks << 2) | kg) ^ ((2 * rr + col) & 7);
          a[u] = *reinterpret_cast<const bf16x8*>(smem + Y1OFF + (rr * 18 + col) * 128 +
                                                  slot * 16);
        }
#pragma unroll
        for (int kh = 0; kh < 3; ++kh) {
          bf16x8 bw[2];
#pragma unroll
          for (int j = 0; j < 2; ++j)
            bw[j] = __builtin_bit_cast(
                bf16x8,
                *reinterpret_cast<const u16x8*>(
                    weff2 + (((kh * 3 + kw) * 64 + (nf0 + j) * 16 + ol) * 64 + ks * 32 +
                             kg * 8)));
#pragma unroll
          for (int mf = 0; mf < 4; ++mf)
#pragma unroll
            for (int j = 0; j < 2; ++j)
              acc2[mf][j] = __builtin_amdgcn_mfma_f32_16x16x32_bf16(
                  a[mf + kh], bw[j], acc2[mf][j], 0, 0, 0);
        }
      }

    // ---- bn2 + residual (from staged input LDS) + relu -> direct stores ----
#pragma unroll
    for (int mf = 0; mf < 4; ++mf) {
      int R = f0 + mf;
      int h = th0[t] + R;
#pragma unroll
      for (int j = 0; j < 2; ++j) {
        int oc = (nf0 + j) * 16 + ol;
        f32x4 vv;
#pragma unroll
        for (int rg = 0; rg < 4; ++rg) {
          int W = kg * 4 + rg;
          int wr = R + 2, wc = W + 2;
          int key = (2 * wr + wc + 5) & 7;
          u16 xb16 = *reinterpret_cast<const u16*>(
              smem + (wr * 20 + wc) * 128 + ((oc >> 3) ^ key) * 16 + (oc & 7) * 2);
          vv[rg] = fmaxf(acc2[mf][j][rg] * inv2[j] + bias2[j] + b2f(xb16), 0.f);
        }
        *reinterpret_cast<f32x4*>(out + (((tb[t] * 64 + oc) * NH + h) * NW + tw0[t] +
                                         kg * 4)) = vv;
      }
    }

    if (t < TILES - 1) {
      SCHEDB;
      __builtin_amdgcn_s_barrier();  // input+y1 reads done -> safe to restage
      SCHEDB;
    }
  }
}

// ---------------------------------------------------------------------------
extern "C" void kernel_launch(void* const* d_in, const int* in_sizes, int n_in,
                              void* d_out, int out_size, void* d_ws, size_t ws_size,
                              hipStream_t stream) {
  const float* x = (const float*)d_in[0];
  const float* w1 = (const float*)d_in[1];
  const float* w2 = (const float*)d_in[2];
  const float* alpha = (const float*)d_in[3];
  const float* g1 = (const float*)d_in[4];
  const float* b1 = (const float*)d_in[5];
  const float* m1 = (const float*)d_in[6];
  const float* v1 = (const float*)d_in[7];
  const float* g2 = (const float*)d_in[8];
  const float* b2 = (const float*)d_in[9];
  const float* m2 = (const float*)d_in[10];
  const float* v2 = (const float*)d_in[11];
  float* out = (float*)d_out;

  char* ws = (char*)d_ws;
  u16* weff1 = (u16*)ws;               // 73728 B
  u16* weff2 = (u16*)(ws + 73728);     // 73728 B
  float* bnc = (float*)(ws + 147456);  // 1024 B
  u16* xpad = (u16*)(ws + 148480);     // 32*114*114*64*2 = 53231616 B

  border_zero<<<452, 256, 0, stream>>>(xpad);
  transform_kernel<<<32 * NH, 256, 0, stream>>>(x, xpad);
  prep_kernel<<<144, 256, 0, stream>>>(w1, w2, alpha, g1, b1, m1, v1,
                                       g2, b2, m2, v2, weff1, weff2, bnc);
  fused_kernel<2><<<1568, 256, 0, stream>>>(xpad, weff1, weff2, bnc, out);
}

// Round 13
// 160.595 us; speedup vs baseline: 4.3951x; 4.3951x over previous
//
#include <hip/hip_runtime.h>

// BasicBlock: y = relu(bn2(conv2(relu(bn1(conv1(x, we1))), we2)) + x)
// we{1,2} = sum_e alpha[e]*w{1,2}[e].
//
// bf16 implicit-GEMM conv, mfma_f32_16x16x32_bf16, staged from padded,
// chunk-swizzled NHWC bf16 images (slot = c8 ^ ((2h+w)&7) within 128B px).
//
// R13 = R6 verbatim (the session's measured optimum, 155us; all later
// structural variants — deeper tile pipelines, occupancy caps, fused
// conv1+conv2 — regressed via VGPR-128 spill traffic or grid-tail).
//  - t=0 gate: wait vmcnt(6/5) where the ONLY younger VMEM ops are stage1's
//    loads (loads retire oldest-first -> sound).
//  - stage1 drain: vmcnt(0) at END of compute(t0), before epilogue VMEM
//    (loads-only window; nearly free since compute(t0) covered the latency).
// Weights preloaded to registers (36 bf16x8/wave) so the K-loop has no VMEM.

typedef __bf16 bf16x8 __attribute__((ext_vector_type(8)));
typedef float f32x4 __attribute__((ext_vector_type(4)));
typedef unsigned short u16;
typedef u16 u16x8 __attribute__((ext_vector_type(8)));

#define NH 112
#define NW 112
#define PH 114
#define PW 114
#define PROWB (PW * 128)  // 14592 bytes per padded NHWC row
#define BUFB 23040        // one A-tile buffer: 10 rows * 18 px * 128 B

__device__ __forceinline__ u16 f2b(float f) {
  unsigned u = __builtin_bit_cast(unsigned, f);
  u += 0x7FFFu + ((u >> 16) & 1u);
  return (u16)(u >> 16);
}

__device__ __forceinline__ void gl_lds16(const void* g, void* l) {
  __builtin_amdgcn_global_load_lds(
      (const __attribute__((address_space(1))) unsigned int*)g,
      (__attribute__((address_space(3))) unsigned int*)l, 16, 0, 0);
}

// ---------------------------------------------------------------------------
__global__ void border_zero(u16* __restrict__ a, u16* __restrict__ bbuf) {
  int idx = blockIdx.x * 256 + threadIdx.x;  // 2*32*452*8 = 231424 chunks
  if (idx >= 231424) return;
  int c8 = idx & 7;
  int t = idx >> 3;
  int buf = t >= 14464;
  t -= buf * 14464;
  int img = t / 452, e = t % 452;
  int h, w;
  if (e < 114) { h = 0; w = e; }
  else if (e < 228) { h = 113; w = e - 114; }
  else if (e < 340) { h = e - 227; w = 0; }
  else { h = e - 339; w = 113; }
  u16* base = buf ? bbuf : a;
  u16x8 z = {0, 0, 0, 0, 0, 0, 0, 0};
  *reinterpret_cast<u16x8*>(base + (((long)img * PH + h) * PW + w) * 64 + c8 * 8) = z;
}

// ---------------------------------------------------------------------------
// x NCHW fp32 -> x_pad NHWC bf16 (padded + chunk-swizzled). block = (b,h).
__global__ __launch_bounds__(256) void transform_kernel(const float* __restrict__ x,
                                                        u16* __restrict__ xpad) {
  __shared__ alignas(16) u16 t[7168];  // [112 px][64 ch], xor-swizzled bytes
  int tid = threadIdx.x, bid = blockIdx.x;
  int b = bid / NH, h = bid % NH;
  const float* src = x + (long)b * 64 * 12544 + h * NW;
  f32x4 v[7];
#pragma unroll
  for (int it = 0; it < 7; ++it) {
    int fid = it * 256 + tid;  // 1792 = 64 ch * 28 quads
    int c = fid / 28, wq = fid % 28;
    v[it] = *reinterpret_cast<const f32x4*>(src + c * 12544 + wq * 4);
  }
#pragma unroll
  for (int it = 0; it < 7; ++it) {
    int fid = it * 256 + tid;
    int c = fid / 28, wq = fid % 28;
    int key = (wq & 7) << 4;
#pragma unroll
    for (int j = 0; j < 4; ++j) {
      int px = wq * 4 + j;
      *reinterpret_cast<u16*>((char*)t + px * 128 + ((c * 2) ^ key)) = f2b(v[it][j]);
    }
  }
  __syncthreads();
  int hp = h + 1;
  u16* rowb = xpad + (((long)b * PH + hp) * PW) * 64;
#pragma unroll
  for (int it = 0; it < 4; ++it) {
    int cidx = it * 256 + tid;
    if (cidx < 896) {  // 112 px * 8 chunks
      int c8 = cidx & 7, px = cidx >> 3;
      int lchunk = c8 ^ ((px >> 2) & 7);
      u16x8 vv = *reinterpret_cast<const u16x8*>((const char*)t + px * 128 + lchunk * 16);
      int wp = px + 1;
      int gkey = (2 * hp + wp) & 7;
      *reinterpret_cast<u16x8*>(rowb + (long)wp * 64 + ((c8 ^ gkey) * 8)) = vv;
    }
  }
}

// ---------------------------------------------------------------------------
// fold experts -> w_eff bf16 [kpos][o][i] + folded BN constants
__global__ void prep_kernel(
    const float* __restrict__ w1, const float* __restrict__ w2,
    const float* __restrict__ alpha,
    const float* __restrict__ g1, const float* __restrict__ b1,
    const float* __restrict__ m1, const float* __restrict__ v1,
    const float* __restrict__ g2, const float* __restrict__ b2,
    const float* __restrict__ m2, const float* __restrict__ v2,
    u16* __restrict__ weff1, u16* __restrict__ weff2, float* __restrict__ bnc) {
  int idx = blockIdx.x * 256 + threadIdx.x;  // 36864
  if (idx < 36864) {
    int i = idx & 63;
    int o = (idx >> 6) & 63;
    int kpos = idx >> 12;
    int base = (o * 64 + i) * 9 + kpos;  // src [E][O][I][3][3]
    float a1 = 0.f, a2 = 0.f;
#pragma unroll
    for (int e = 0; e < 10; ++e) {
      float al = alpha[e];
      a1 += al * w1[e * 36864 + base];
      a2 += al * w2[e * 36864 + base];
    }
    weff1[idx] = f2b(a1);
    weff2[idx] = f2b(a2);
  }
  if (blockIdx.x == 0 && threadIdx.x < 64) {
    int c = threadIdx.x;
    float i1 = g1[c] * rsqrtf(v1[c] + 1e-5f);
    float i2 = g2[c] * rsqrtf(v2[c] + 1e-5f);
    bnc[c] = i1;
    bnc[64 + c] = b1[c] - m1[c] * i1;
    bnc[128 + c] = i2;
    bnc[192 + c] = b2[c] - m2[c] * i2;
  }
}

// ---------------------------------------------------------------------------
// conv pass. 8x16 px x 64 oc per tile, 2 tiles/block (double-buffered),
// 256 threads (4 waves: wave = 4 Mfrags(rows) x 2 Nfrags), grid 1568.
// PASS 0: xin=x_pad -> bn1+relu -> y1_pad (swizzled NHWC bf16)
// PASS 1: xin=y1_pad -> bn2 + residual(x) + relu -> out (NCHW f32)
// ---------------------------------------------------------------------------
template <int PASS>
__global__ __launch_bounds__(256, 2) void conv_bn_kernel(
    const u16* __restrict__ xin, const float* __restrict__ x,
    const u16* __restrict__ weff, const float* __restrict__ bnc,
    u16* __restrict__ ypad, float* __restrict__ out) {
  __shared__ alignas(64) char smem[2 * BUFB];

  int tid = threadIdx.x, lane = tid & 63, wv = tid >> 6;
  int ol = lane & 15, kg = (lane >> 4) & 3;
  int f0 = (wv >> 1) * 4, nf0 = (wv & 1) * 2;

  // ---- BN consts + weights -> registers; drain so the K-loop has no VMEM ----
  float inv[2], bias[2];
#pragma unroll
  for (int j = 0; j < 2; ++j) {
    int o = (nf0 + j) * 16 + ol;
    inv[j] = bnc[PASS * 128 + o];
    bias[j] = bnc[PASS * 128 + 64 + o];
  }
  bf16x8 wf[3][3][2][2];  // [kh][kw][ks][nf-local]
#pragma unroll
  for (int kh = 0; kh < 3; ++kh)
#pragma unroll
    for (int kw = 0; kw < 3; ++kw)
#pragma unroll
      for (int ks = 0; ks < 2; ++ks)
#pragma unroll
        for (int j = 0; j < 2; ++j)
          wf[kh][kw][ks][j] = __builtin_bit_cast(
              bf16x8, *reinterpret_cast<const u16x8*>(
                          weff + (((kh * 3 + kw) * 64 + (nf0 + j) * 16 + ol) * 64 +
                                  ks * 32 + kg * 8)));
  asm volatile("s_waitcnt vmcnt(0)" ::: "memory");
  __builtin_amdgcn_sched_barrier(0);

  // ---- tile decode (XCD-chunked swizzle; 1568 = 8*196 bijective) ----
  int sb = (blockIdx.x & 7) * 196 + (blockIdx.x >> 3);
  int tb[2], th0[2], tw0[2];
#pragma unroll
  for (int t = 0; t < 2; ++t) {
    int tt = sb * 2 + t;
    tb[t] = tt / 98;
    int r = tt % 98;
    th0[t] = (r / 7) * 8;
    tw0[t] = (r % 7) * 16;
  }

  // stage one 10x18 window (1440 chunks; waves issue 6,6,6,5 insts)
  auto stage = [&](int t, int boff) {
#pragma unroll
    for (int k = 0; k < 6; ++k) {
      int i = wv + k * 4;
      if (i < 23) {
        int cb = i * 64 + lane;
        if (cb < 1440) {
          int row = cb / 144, rem = cb % 144;
          gl_lds16((const char*)(xin + (((long)tb[t] * PH + th0[t]) * PW + tw0[t]) * 64) +
                       (long)row * PROWB + rem * 16,
                   smem + boff + cb * 16);
        }
      }
    }
  };

  stage(0, 0);
  asm volatile("" ::: "memory");  // keep stage0 | stage1 issue groups ordered
  stage(1, BUFB);                 // in flight across compute(t0)
  asm volatile("" ::: "memory");
  // own stage0 done: younger ops = own stage1 = 6 loads (wave3: 5), loads-only
  if (wv < 3) asm volatile("s_waitcnt vmcnt(6)" ::: "memory");
  else        asm volatile("s_waitcnt vmcnt(5)" ::: "memory");
  __builtin_amdgcn_sched_barrier(0);

#pragma unroll
  for (int t = 0; t < 2; ++t) {
    const int boff = t * BUFB;
    __builtin_amdgcn_s_barrier();  // all waves' tile-t data landed & visible
    __builtin_amdgcn_sched_barrier(0);

    // ---- MFMA: per (kw,ks) load 6 row-frags, 24 MFMA reusing them ----
    f32x4 acc[4][2];
#pragma unroll
    for (int mf = 0; mf < 4; ++mf)
#pragma unroll
      for (int j = 0; j < 2; ++j) acc[mf][j] = f32x4{0.f, 0.f, 0.f, 0.f};

#pragma unroll
    for (int kw = 0; kw < 3; ++kw)
#pragma unroll
      for (int ks = 0; ks < 2; ++ks) {
        bf16x8 a[6];
#pragma unroll
        for (int u = 0; u < 6; ++u) {
          int rr = f0 + u, col = ol + kw;
          int slot = ((ks << 2) | kg) ^ ((2 * rr + col) & 7);
          a[u] = *reinterpret_cast<const bf16x8*>(smem + boff +
                                                  (rr * 18 + col) * 128 + slot * 16);
        }
#pragma unroll
        for (int kh = 0; kh < 3; ++kh)
#pragma unroll
          for (int mf = 0; mf < 4; ++mf)
#pragma unroll
            for (int j = 0; j < 2; ++j)
              acc[mf][j] = __builtin_amdgcn_mfma_f32_16x16x32_bf16(
                  a[mf + kh], wf[kh][kw][ks][j], acc[mf][j], 0, 0, 0);
      }

    if (t == 0) {
      // drain stage1 (loads-only window; latency covered by compute above)
      asm volatile("s_waitcnt vmcnt(0)" ::: "memory");
      __builtin_amdgcn_sched_barrier(0);
    }

    // ---- epilogue ----
    if constexpr (PASS == 0) {
      __builtin_amdgcn_sched_barrier(0);
      __builtin_amdgcn_s_barrier();  // all waves done reading buf[t]: reuse it
      __builtin_amdgcn_sched_barrier(0);
      u16* ys = reinterpret_cast<u16*>(smem + boff);  // [128 px][72]
#pragma unroll
      for (int mf = 0; mf < 4; ++mf)
#pragma unroll
        for (int j = 0; j < 2; ++j) {
          int o = (nf0 + j) * 16 + ol;
#pragma unroll
          for (int rg = 0; rg < 4; ++rg) {
            int p = (f0 + mf) * 16 + kg * 4 + rg;
            ys[p * 72 + o] = f2b(fmaxf(acc[mf][j][rg] * inv[j] + bias[j], 0.f));
          }
        }
      asm volatile("s_waitcnt lgkmcnt(0)" ::: "memory");
      __builtin_amdgcn_sched_barrier(0);
      __builtin_amdgcn_s_barrier();
      __builtin_amdgcn_sched_barrier(0);
#pragma unroll
      for (int it = 0; it < 4; ++it) {
        int cidx = it * 256 + tid;  // 1024 chunks
        int c8 = cidx & 7, p = cidx >> 3;
        int hp = th0[t] + (p >> 4) + 1, wp = tw0[t] + (p & 15) + 1;
        int gkey = (2 * hp + wp) & 7;
        *reinterpret_cast<u16x8*>(ypad + (((long)tb[t] * PH + hp) * PW + wp) * 64 +
                                  ((c8 ^ gkey) * 8)) =
            *reinterpret_cast<const u16x8*>(ys + p * 72 + c8 * 8);
      }
    } else {
      // direct: D-frag row rg = pixel (th0+f0+mf, tw0+kg*4+rg), oc = nf*16+ol
#pragma unroll
      for (int half = 0; half < 2; ++half) {
        f32x4 xr[2][2];
#pragma unroll
        for (int m = 0; m < 2; ++m) {
          int h = th0[t] + f0 + half * 2 + m;
#pragma unroll
          for (int j = 0; j < 2; ++j)
            xr[m][j] = *reinterpret_cast<const f32x4*>(
                x + (((tb[t] * 64 + (nf0 + j) * 16 + ol) * NH + h) * NW + tw0[t] +
                     kg * 4));
        }
#pragma unroll
        for (int m = 0; m < 2; ++m) {
          int mf = half * 2 + m;
          int h = th0[t] + f0 + mf;
#pragma unroll
          for (int j = 0; j < 2; ++j) {
            f32x4 vv;
#pragma unroll
            for (int rg = 0; rg < 4; ++rg)
              vv[rg] = fmaxf(acc[mf][j][rg] * inv[j] + bias[j] + xr[m][j][rg], 0.f);
            *reinterpret_cast<f32x4*>(
                out + (((tb[t] * 64 + (nf0 + j) * 16 + ol) * NH + h) * NW + tw0[t] +
                       kg * 4)) = vv;
          }
        }
      }
    }
  }
}

// ---------------------------------------------------------------------------
extern "C" void kernel_launch(void* const* d_in, const int* in_sizes, int n_in,
                              void* d_out, int out_size, void* d_ws, size_t ws_size,
                              hipStream_t stream) {
  const float* x = (const float*)d_in[0];
  const float* w1 = (const float*)d_in[1];
  const float* w2 = (const float*)d_in[2];
  const float* alpha = (const float*)d_in[3];
  const float* g1 = (const float*)d_in[4];
  const float* b1 = (const float*)d_in[5];
  const float* m1 = (const float*)d_in[6];
  const float* v1 = (const float*)d_in[7];
  const float* g2 = (const float*)d_in[8];
  const float* b2 = (const float*)d_in[9];
  const float* m2 = (const float*)d_in[10];
  const float* v2 = (const float*)d_in[11];
  float* out = (float*)d_out;

  char* ws = (char*)d_ws;
  u16* weff1 = (u16*)ws;                 // 73728 B
  u16* weff2 = (u16*)(ws + 73728);       // 73728 B
  float* bnc = (float*)(ws + 147456);    // 1024 B
  u16* y1pad = (u16*)(ws + 148480);      // 32*114*114*64*2 = 53231616 B
  u16* xpad = (u16*)d_out;               // 53 MB <= 103 MB; dead before P1 writes

  border_zero<<<904, 256, 0, stream>>>(xpad, y1pad);
  transform_kernel<<<32 * NH, 256, 0, stream>>>(x, xpad);
  prep_kernel<<<144, 256, 0, stream>>>(w1, w2, alpha, g1, b1, m1, v1,
                                       g2, b2, m2, v2, weff1, weff2, bnc);
  conv_bn_kernel<0><<<1568, 256, 0, stream>>>(xpad, x, weff1, bnc, y1pad, nullptr);
  conv_bn_kernel<1><<<1568, 256, 0, stream>>>(y1pad, x, weff2, bnc, nullptr, out);
}

// Round 14
// 137.738 us; speedup vs baseline: 5.1244x; 1.1660x over previous
//
#include <hip/hip_runtime.h>

// BasicBlock: y = relu(bn2(conv2(relu(bn1(conv1(x, we1))), we2)) + x)
// we{1,2} = sum_e alpha[e]*w{1,2}[e].
//
// bf16 implicit-GEMM conv, mfma_f32_16x16x32_bf16, staged from padded,
// chunk-swizzled NHWC bf16 images (slot = c8 ^ ((2h+w)&7) within 128B px).
//
// R14 = R6/R13 schedule with the wave decomposition remapped 4Mx2N -> 8Mx1N:
// each wave computes all 8 M-frags for ONE 16-oc fragment (nf = wave id).
// Weight residency drops 36 -> 18 bf16x8 (144 -> 72 VGPR); A-frags use a
// 4-slot rolling window (16 VGPR, compile-time indices). Peak live ~135 vs
// ~219 before: kills the ~100MB/pass spill round-trip visible in R13's
// counters (P0 FETCH 107 vs 67 ideal, WRITE 119 vs 51 ideal).
// Schedule/gates unchanged (proven sound since R6):
//  - t=0 gate: vmcnt(6/5), younger VMEM = stage1's loads only.
//  - stage1 drain: vmcnt(0) at END of compute(t0), loads-only window.

typedef __bf16 bf16x8 __attribute__((ext_vector_type(8)));
typedef float f32x4 __attribute__((ext_vector_type(4)));
typedef unsigned short u16;
typedef u16 u16x8 __attribute__((ext_vector_type(8)));

#define NH 112
#define NW 112
#define PH 114
#define PW 114
#define PROWB (PW * 128)  // 14592 bytes per padded NHWC row
#define BUFB 23040        // one A-tile buffer: 10 rows * 18 px * 128 B

__device__ __forceinline__ u16 f2b(float f) {
  unsigned u = __builtin_bit_cast(unsigned, f);
  u += 0x7FFFu + ((u >> 16) & 1u);
  return (u16)(u >> 16);
}

__device__ __forceinline__ void gl_lds16(const void* g, void* l) {
  __builtin_amdgcn_global_load_lds(
      (const __attribute__((address_space(1))) unsigned int*)g,
      (__attribute__((address_space(3))) unsigned int*)l, 16, 0, 0);
}

// ---------------------------------------------------------------------------
__global__ void border_zero(u16* __restrict__ a, u16* __restrict__ bbuf) {
  int idx = blockIdx.x * 256 + threadIdx.x;  // 2*32*452*8 = 231424 chunks
  if (idx >= 231424) return;
  int c8 = idx & 7;
  int t = idx >> 3;
  int buf = t >= 14464;
  t -= buf * 14464;
  int img = t / 452, e = t % 452;
  int h, w;
  if (e < 114) { h = 0; w = e; }
  else if (e < 228) { h = 113; w = e - 114; }
  else if (e < 340) { h = e - 227; w = 0; }
  else { h = e - 339; w = 113; }
  u16* base = buf ? bbuf : a;
  u16x8 z = {0, 0, 0, 0, 0, 0, 0, 0};
  *reinterpret_cast<u16x8*>(base + (((long)img * PH + h) * PW + w) * 64 + c8 * 8) = z;
}

// ---------------------------------------------------------------------------
// x NCHW fp32 -> x_pad NHWC bf16 (padded + chunk-swizzled). block = (b,h).
__global__ __launch_bounds__(256) void transform_kernel(const float* __restrict__ x,
                                                        u16* __restrict__ xpad) {
  __shared__ alignas(16) u16 t[7168];  // [112 px][64 ch], xor-swizzled bytes
  int tid = threadIdx.x, bid = blockIdx.x;
  int b = bid / NH, h = bid % NH;
  const float* src = x + (long)b * 64 * 12544 + h * NW;
  f32x4 v[7];
#pragma unroll
  for (int it = 0; it < 7; ++it) {
    int fid = it * 256 + tid;  // 1792 = 64 ch * 28 quads
    int c = fid / 28, wq = fid % 28;
    v[it] = *reinterpret_cast<const f32x4*>(src + c * 12544 + wq * 4);
  }
#pragma unroll
  for (int it = 0; it < 7; ++it) {
    int fid = it * 256 + tid;
    int c = fid / 28, wq = fid % 28;
    int key = (wq & 7) << 4;
#pragma unroll
    for (int j = 0; j < 4; ++j) {
      int px = wq * 4 + j;
      *reinterpret_cast<u16*>((char*)t + px * 128 + ((c * 2) ^ key)) = f2b(v[it][j]);
    }
  }
  __syncthreads();
  int hp = h + 1;
  u16* rowb = xpad + (((long)b * PH + hp) * PW) * 64;
#pragma unroll
  for (int it = 0; it < 4; ++it) {
    int cidx = it * 256 + tid;
    if (cidx < 896) {  // 112 px * 8 chunks
      int c8 = cidx & 7, px = cidx >> 3;
      int lchunk = c8 ^ ((px >> 2) & 7);
      u16x8 vv = *reinterpret_cast<const u16x8*>((const char*)t + px * 128 + lchunk * 16);
      int wp = px + 1;
      int gkey = (2 * hp + wp) & 7;
      *reinterpret_cast<u16x8*>(rowb + (long)wp * 64 + ((c8 ^ gkey) * 8)) = vv;
    }
  }
}

// ---------------------------------------------------------------------------
// fold experts -> w_eff bf16 [kpos][o][i] + folded BN constants
__global__ void prep_kernel(
    const float* __restrict__ w1, const float* __restrict__ w2,
    const float* __restrict__ alpha,
    const float* __restrict__ g1, const float* __restrict__ b1,
    const float* __restrict__ m1, const float* __restrict__ v1,
    const float* __restrict__ g2, const float* __restrict__ b2,
    const float* __restrict__ m2, const float* __restrict__ v2,
    u16* __restrict__ weff1, u16* __restrict__ weff2, float* __restrict__ bnc) {
  int idx = blockIdx.x * 256 + threadIdx.x;  // 36864
  if (idx < 36864) {
    int i = idx & 63;
    int o = (idx >> 6) & 63;
    int kpos = idx >> 12;
    int base = (o * 64 + i) * 9 + kpos;  // src [E][O][I][3][3]
    float a1 = 0.f, a2 = 0.f;
#pragma unroll
    for (int e = 0; e < 10; ++e) {
      float al = alpha[e];
      a1 += al * w1[e * 36864 + base];
      a2 += al * w2[e * 36864 + base];
    }
    weff1[idx] = f2b(a1);
    weff2[idx] = f2b(a2);
  }
  if (blockIdx.x == 0 && threadIdx.x < 64) {
    int c = threadIdx.x;
    float i1 = g1[c] * rsqrtf(v1[c] + 1e-5f);
    float i2 = g2[c] * rsqrtf(v2[c] + 1e-5f);
    bnc[c] = i1;
    bnc[64 + c] = b1[c] - m1[c] * i1;
    bnc[128 + c] = i2;
    bnc[192 + c] = b2[c] - m2[c] * i2;
  }
}

// ---------------------------------------------------------------------------
// conv pass. 8x16 px x 64 oc per tile, 2 tiles/block (double-buffered),
// 256 threads; wave wv = all 8 Mfrags x 1 Nfrag (oc wv*16..wv*16+15).
// grid 1568. PASS 0: x_pad -> bn1+relu -> y1_pad (swizzled NHWC bf16)
//            PASS 1: y1_pad -> bn2 + residual(x) + relu -> out (NCHW f32)
// ---------------------------------------------------------------------------
template <int PASS>
__global__ __launch_bounds__(256, 2) void conv_bn_kernel(
    const u16* __restrict__ xin, const float* __restrict__ x,
    const u16* __restrict__ weff, const float* __restrict__ bnc,
    u16* __restrict__ ypad, float* __restrict__ out) {
  __shared__ alignas(64) char smem[2 * BUFB];

  int tid = threadIdx.x, lane = tid & 63, wv = tid >> 6;
  int ol = lane & 15, kg = (lane >> 4) & 3;
  const int o = wv * 16 + ol;  // this lane's output channel

  // ---- BN consts + weights -> registers; drain so the K-loop has no VMEM ----
  float inv = bnc[PASS * 128 + o];
  float bias = bnc[PASS * 128 + 64 + o];

  bf16x8 wf[3][3][2];  // [kh][kw][ks] — 18 frags = 72 VGPR (fits!)
#pragma unroll
  for (int kh = 0; kh < 3; ++kh)
#pragma unroll
    for (int kw = 0; kw < 3; ++kw)
#pragma unroll
      for (int ks = 0; ks < 2; ++ks)
        wf[kh][kw][ks] = __builtin_bit_cast(
            bf16x8, *reinterpret_cast<const u16x8*>(
                        weff + (((kh * 3 + kw) * 64 + o) * 64 + ks * 32 + kg * 8)));
  asm volatile("s_waitcnt vmcnt(0)" ::: "memory");
  __builtin_amdgcn_sched_barrier(0);

  // ---- tile decode (XCD-chunked swizzle; 1568 = 8*196 bijective) ----
  int sb = (blockIdx.x & 7) * 196 + (blockIdx.x >> 3);
  int tb[2], th0[2], tw0[2];
#pragma unroll
  for (int t = 0; t < 2; ++t) {
    int tt = sb * 2 + t;
    tb[t] = tt / 98;
    int r = tt % 98;
    th0[t] = (r / 7) * 8;
    tw0[t] = (r % 7) * 16;
  }

  // stage one 10x18 window (1440 chunks; waves issue 6,6,6,5 insts)
  auto stage = [&](int t, int boff) {
#pragma unroll
    for (int k = 0; k < 6; ++k) {
      int i = wv + k * 4;
      if (i < 23) {
        int cb = i * 64 + lane;
        if (cb < 1440) {
          int row = cb / 144, rem = cb % 144;
          gl_lds16((const char*)(xin + (((long)tb[t] * PH + th0[t]) * PW + tw0[t]) * 64) +
                       (long)row * PROWB + rem * 16,
                   smem + boff + cb * 16);
        }
      }
    }
  };

  stage(0, 0);
  asm volatile("" ::: "memory");  // keep stage0 | stage1 issue groups ordered
  stage(1, BUFB);                 // in flight across compute(t0)
  asm volatile("" ::: "memory");
  // own stage0 done: younger ops = own stage1 = 6 loads (wave3: 5), loads-only
  if (wv < 3) asm volatile("s_waitcnt vmcnt(6)" ::: "memory");
  else        asm volatile("s_waitcnt vmcnt(5)" ::: "memory");
  __builtin_amdgcn_sched_barrier(0);

#pragma unroll
  for (int t = 0; t < 2; ++t) {
    const int boff = t * BUFB;
    __builtin_amdgcn_s_barrier();  // all waves' tile-t data landed & visible
    __builtin_amdgcn_sched_barrier(0);

    // ---- MFMA: rows 0..9, rolling 4-slot A window; acc[mf] = out row mf ----
    f32x4 acc[8];
#pragma unroll
    for (int mf = 0; mf < 8; ++mf) acc[mf] = f32x4{0.f, 0.f, 0.f, 0.f};

#pragma unroll
    for (int kw = 0; kw < 3; ++kw)
#pragma unroll
      for (int ks = 0; ks < 2; ++ks) {
        const int col = ol + kw;
        const int sb8 = (ks << 2) | kg;
        bf16x8 a[4];
#pragma unroll
        for (int u = 0; u < 3; ++u) {
          int slot = sb8 ^ ((2 * u + col) & 7);
          a[u] = *reinterpret_cast<const bf16x8*>(smem + boff + (u * 18 + col) * 128 +
                                                  slot * 16);
        }
#pragma unroll
        for (int mf = 0; mf < 8; ++mf) {
          if (mf < 7) {  // row mf+3 into the slot row mf just vacated
            int rr = mf + 3;
            int slot = sb8 ^ ((2 * rr + col) & 7);
            a[(mf + 3) & 3] = *reinterpret_cast<const bf16x8*>(
                smem + boff + (rr * 18 + col) * 128 + slot * 16);
          }
          acc[mf] = __builtin_amdgcn_mfma_f32_16x16x32_bf16(a[mf & 3], wf[0][kw][ks],
                                                            acc[mf], 0, 0, 0);
          acc[mf] = __builtin_amdgcn_mfma_f32_16x16x32_bf16(a[(mf + 1) & 3], wf[1][kw][ks],
                                                            acc[mf], 0, 0, 0);
          acc[mf] = __builtin_amdgcn_mfma_f32_16x16x32_bf16(a[(mf + 2) & 3], wf[2][kw][ks],
                                                            acc[mf], 0, 0, 0);
        }
      }

    if (t == 0) {
      // drain stage1 (loads-only window; latency covered by compute above)
      asm volatile("s_waitcnt vmcnt(0)" ::: "memory");
      __builtin_amdgcn_sched_barrier(0);
    }

    // ---- epilogue ----
    if constexpr (PASS == 0) {
      __builtin_amdgcn_sched_barrier(0);
      __builtin_amdgcn_s_barrier();  // all waves done reading buf[t]: reuse it
      __builtin_amdgcn_sched_barrier(0);
      u16* ys = reinterpret_cast<u16*>(smem + boff);  // [128 px][72]
#pragma unroll
      for (int mf = 0; mf < 8; ++mf)
#pragma unroll
        for (int rg = 0; rg < 4; ++rg) {
          int p = mf * 16 + kg * 4 + rg;
          ys[p * 72 + o] = f2b(fmaxf(acc[mf][rg] * inv + bias, 0.f));
        }
      asm volatile("s_waitcnt lgkmcnt(0)" ::: "memory");
      __builtin_amdgcn_sched_barrier(0);
      __builtin_amdgcn_s_barrier();
      __builtin_amdgcn_sched_barrier(0);
#pragma unroll
      for (int it = 0; it < 4; ++it) {
        int cidx = it * 256 + tid;  // 1024 chunks
        int c8 = cidx & 7, p = cidx >> 3;
        int hp = th0[t] + (p >> 4) + 1, wp = tw0[t] + (p & 15) + 1;
        int gkey = (2 * hp + wp) & 7;
        *reinterpret_cast<u16x8*>(ypad + (((long)tb[t] * PH + hp) * PW + wp) * 64 +
                                  ((c8 ^ gkey) * 8)) =
            *reinterpret_cast<const u16x8*>(ys + p * 72 + c8 * 8);
      }
    } else {
      // direct: acc[mf] row rg = pixel (th0+mf, tw0+kg*4+rg), channel o
#pragma unroll
      for (int half = 0; half < 2; ++half) {
        f32x4 xr[4];
#pragma unroll
        for (int m = 0; m < 4; ++m) {
          int h = th0[t] + half * 4 + m;
          xr[m] = *reinterpret_cast<const f32x4*>(
              x + (((tb[t] * 64 + o) * NH + h) * NW + tw0[t] + kg * 4));
        }
#pragma unroll
        for (int m = 0; m < 4; ++m) {
          int mf = half * 4 + m;
          int h = th0[t] + mf;
          f32x4 vv;
#pragma unroll
          for (int rg = 0; rg < 4; ++rg)
            vv[rg] = fmaxf(acc[mf][rg] * inv + bias + xr[m][rg], 0.f);
          *reinterpret_cast<f32x4*>(
              out + (((tb[t] * 64 + o) * NH + h) * NW + tw0[t] + kg * 4)) = vv;
        }
      }
    }
  }
}

// ---------------------------------------------------------------------------
extern "C" void kernel_launch(void* const* d_in, const int* in_sizes, int n_in,
                              void* d_out, int out_size, void* d_ws, size_t ws_size,
                              hipStream_t stream) {
  const float* x = (const float*)d_in[0];
  const float* w1 = (const float*)d_in[1];
  const float* w2 = (const float*)d_in[2];
  const float* alpha = (const float*)d_in[3];
  const float* g1 = (const float*)d_in[4];
  const float* b1 = (const float*)d_in[5];
  const float* m1 = (const float*)d_in[6];
  const float* v1 = (const float*)d_in[7];
  const float* g2 = (const float*)d_in[8];
  const float* b2 = (const float*)d_in[9];
  const float* m2 = (const float*)d_in[10];
  const float* v2 = (const float*)d_in[11];
  float* out = (float*)d_out;

  char* ws = (char*)d_ws;
  u16* weff1 = (u16*)ws;                 // 73728 B
  u16* weff2 = (u16*)(ws + 73728);       // 73728 B
  float* bnc = (float*)(ws + 147456);    // 1024 B
  u16* y1pad = (u16*)(ws + 148480);      // 32*114*114*64*2 = 53231616 B
  u16* xpad = (u16*)d_out;               // 53 MB <= 103 MB; dead before P1 writes

  border_zero<<<904, 256, 0, stream>>>(xpad, y1pad);
  transform_kernel<<<32 * NH, 256, 0, stream>>>(x, xpad);
  prep_kernel<<<144, 256, 0, stream>>>(w1, w2, alpha, g1, b1, m1, v1,
                                       g2, b2, m2, v2, weff1, weff2, bnc);
  conv_bn_kernel<0><<<1568, 256, 0, stream>>>(xpad, x, weff1, bnc, y1pad, nullptr);
  conv_bn_kernel<1><<<1568, 256, 0, stream>>>(y1pad, x, weff2, bnc, nullptr, out);
}

// Round 15
// 134.319 us; speedup vs baseline: 5.2548x; 1.0254x over previous
//
#include <hip/hip_runtime.h>

// BasicBlock: y = relu(bn2(conv2(relu(bn1(conv1(x, we1))), we2)) + x)
// we{1,2} = sum_e alpha[e]*w{1,2}[e].
//
// bf16 implicit-GEMM conv, mfma_f32_16x16x32_bf16, staged from padded,
// chunk-swizzled NHWC bf16 images (slot = c8 ^ ((2h+w)&7) within 128B px).
//
// R15 = R14 (8Mx1N wave remap, 137.7us: wf 18 frags = 72 VGPR, rolling
// 4-slot A window, VGPR 112, spill-free) + bf16 residual for PASS1:
// residual read from xpad (bf16, L3-resident, 53MB) instead of fp32 x
// (103MB HBM). Runtime ws_size check; fallback = exact R14 behavior.
// Schedule/gates unchanged (proven sound since R6):
//  - t=0 gate: vmcnt(6/5), younger VMEM = stage1's loads only.
//  - stage1 drain: vmcnt(0) at END of compute(t0), loads-only window.

typedef __bf16 bf16x8 __attribute__((ext_vector_type(8)));
typedef float f32x4 __attribute__((ext_vector_type(4)));
typedef unsigned short u16;
typedef u16 u16x8 __attribute__((ext_vector_type(8)));

#define NH 112
#define NW 112
#define PH 114
#define PW 114
#define PROWB (PW * 128)  // 14592 bytes per padded NHWC row
#define BUFB 23040        // one A-tile buffer: 10 rows * 18 px * 128 B

__device__ __forceinline__ u16 f2b(float f) {
  unsigned u = __builtin_bit_cast(unsigned, f);
  u += 0x7FFFu + ((u >> 16) & 1u);
  return (u16)(u >> 16);
}
__device__ __forceinline__ float b2f(u16 b) {
  unsigned u = ((unsigned)b) << 16;
  return __builtin_bit_cast(float, u);
}

__device__ __forceinline__ void gl_lds16(const void* g, void* l) {
  __builtin_amdgcn_global_load_lds(
      (const __attribute__((address_space(1))) unsigned int*)g,
      (__attribute__((address_space(3))) unsigned int*)l, 16, 0, 0);
}

// ---------------------------------------------------------------------------
__global__ void border_zero(u16* __restrict__ a, u16* __restrict__ bbuf) {
  int idx = blockIdx.x * 256 + threadIdx.x;  // 2*32*452*8 = 231424 chunks
  if (idx >= 231424) return;
  int c8 = idx & 7;
  int t = idx >> 3;
  int buf = t >= 14464;
  t -= buf * 14464;
  int img = t / 452, e = t % 452;
  int h, w;
  if (e < 114) { h = 0; w = e; }
  else if (e < 228) { h = 113; w = e - 114; }
  else if (e < 340) { h = e - 227; w = 0; }
  else { h = e - 339; w = 113; }
  u16* base = buf ? bbuf : a;
  u16x8 z = {0, 0, 0, 0, 0, 0, 0, 0};
  *reinterpret_cast<u16x8*>(base + (((long)img * PH + h) * PW + w) * 64 + c8 * 8) = z;
}

// ---------------------------------------------------------------------------
// x NCHW fp32 -> x_pad NHWC bf16 (padded + chunk-swizzled). block = (b,h).
__global__ __launch_bounds__(256) void transform_kernel(const float* __restrict__ x,
                                                        u16* __restrict__ xpad) {
  __shared__ alignas(16) u16 t[7168];  // [112 px][64 ch], xor-swizzled bytes
  int tid = threadIdx.x, bid = blockIdx.x;
  int b = bid / NH, h = bid % NH;
  const float* src = x + (long)b * 64 * 12544 + h * NW;
  f32x4 v[7];
#pragma unroll
  for (int it = 0; it < 7; ++it) {
    int fid = it * 256 + tid;  // 1792 = 64 ch * 28 quads
    int c = fid / 28, wq = fid % 28;
    v[it] = *reinterpret_cast<const f32x4*>(src + c * 12544 + wq * 4);
  }
#pragma unroll
  for (int it = 0; it < 7; ++it) {
    int fid = it * 256 + tid;
    int c = fid / 28, wq = fid % 28;
    int key = (wq & 7) << 4;
#pragma unroll
    for (int j = 0; j < 4; ++j) {
      int px = wq * 4 + j;
      *reinterpret_cast<u16*>((char*)t + px * 128 + ((c * 2) ^ key)) = f2b(v[it][j]);
    }
  }
  __syncthreads();
  int hp = h + 1;
  u16* rowb = xpad + (((long)b * PH + hp) * PW) * 64;
#pragma unroll
  for (int it = 0; it < 4; ++it) {
    int cidx = it * 256 + tid;
    if (cidx < 896) {  // 112 px * 8 chunks
      int c8 = cidx & 7, px = cidx >> 3;
      int lchunk = c8 ^ ((px >> 2) & 7);
      u16x8 vv = *reinterpret_cast<const u16x8*>((const char*)t + px * 128 + lchunk * 16);
      int wp = px + 1;
      int gkey = (2 * hp + wp) & 7;
      *reinterpret_cast<u16x8*>(rowb + (long)wp * 64 + ((c8 ^ gkey) * 8)) = vv;
    }
  }
}

// ---------------------------------------------------------------------------
// fold experts -> w_eff bf16 [kpos][o][i] + folded BN constants
__global__ void prep_kernel(
    const float* __restrict__ w1, const float* __restrict__ w2,
    const float* __restrict__ alpha,
    const float* __restrict__ g1, const float* __restrict__ b1,
    const float* __restrict__ m1, const float* __restrict__ v1,
    const float* __restrict__ g2, const float* __restrict__ b2,
    const float* __restrict__ m2, const float* __restrict__ v2,
    u16* __restrict__ weff1, u16* __restrict__ weff2, float* __restrict__ bnc) {
  int idx = blockIdx.x * 256 + threadIdx.x;  // 36864
  if (idx < 36864) {
    int i = idx & 63;
    int o = (idx >> 6) & 63;
    int kpos = idx >> 12;
    int base = (o * 64 + i) * 9 + kpos;  // src [E][O][I][3][3]
    float a1 = 0.f, a2 = 0.f;
#pragma unroll
    for (int e = 0; e < 10; ++e) {
      float al = alpha[e];
      a1 += al * w1[e * 36864 + base];
      a2 += al * w2[e * 36864 + base];
    }
    weff1[idx] = f2b(a1);
    weff2[idx] = f2b(a2);
  }
  if (blockIdx.x == 0 && threadIdx.x < 64) {
    int c = threadIdx.x;
    float i1 = g1[c] * rsqrtf(v1[c] + 1e-5f);
    float i2 = g2[c] * rsqrtf(v2[c] + 1e-5f);
    bnc[c] = i1;
    bnc[64 + c] = b1[c] - m1[c] * i1;
    bnc[128 + c] = i2;
    bnc[192 + c] = b2[c] - m2[c] * i2;
  }
}

// ---------------------------------------------------------------------------
// conv pass. 8x16 px x 64 oc per tile, 2 tiles/block (double-buffered),
// 256 threads; wave wv = all 8 Mfrags x 1 Nfrag (oc wv*16..wv*16+15).
// grid 1568. PASS 0: x_pad -> bn1+relu -> y1_pad (swizzled NHWC bf16)
//            PASS 1: y1_pad -> bn2 + residual + relu -> out (NCHW f32)
//            RESID=0: residual from fp32 x; RESID=1: from bf16 xpad.
// ---------------------------------------------------------------------------
template <int PASS, int RESID>
__global__ __launch_bounds__(256, 2) void conv_bn_kernel(
    const u16* __restrict__ xin, const float* __restrict__ x,
    const u16* __restrict__ xres, const u16* __restrict__ weff,
    const float* __restrict__ bnc, u16* __restrict__ ypad,
    float* __restrict__ out) {
  __shared__ alignas(64) char smem[2 * BUFB];

  int tid = threadIdx.x, lane = tid & 63, wv = tid >> 6;
  int ol = lane & 15, kg = (lane >> 4) & 3;
  const int o = wv * 16 + ol;  // this lane's output channel

  // ---- BN consts + weights -> registers; drain so the K-loop has no VMEM ----
  float inv = bnc[PASS * 128 + o];
  float bias = bnc[PASS * 128 + 64 + o];

  bf16x8 wf[3][3][2];  // [kh][kw][ks] — 18 frags = 72 VGPR
#pragma unroll
  for (int kh = 0; kh < 3; ++kh)
#pragma unroll
    for (int kw = 0; kw < 3; ++kw)
#pragma unroll
      for (int ks = 0; ks < 2; ++ks)
        wf[kh][kw][ks] = __builtin_bit_cast(
            bf16x8, *reinterpret_cast<const u16x8*>(
                        weff + (((kh * 3 + kw) * 64 + o) * 64 + ks * 32 + kg * 8)));
  asm volatile("s_waitcnt vmcnt(0)" ::: "memory");
  __builtin_amdgcn_sched_barrier(0);

  // ---- tile decode (XCD-chunked swizzle; 1568 = 8*196 bijective) ----
  int sb = (blockIdx.x & 7) * 196 + (blockIdx.x >> 3);
  int tb[2], th0[2], tw0[2];
#pragma unroll
  for (int t = 0; t < 2; ++t) {
    int tt = sb * 2 + t;
    tb[t] = tt / 98;
    int r = tt % 98;
    th0[t] = (r / 7) * 8;
    tw0[t] = (r % 7) * 16;
  }

  // stage one 10x18 window (1440 chunks; waves issue 6,6,6,5 insts)
  auto stage = [&](int t, int boff) {
#pragma unroll
    for (int k = 0; k < 6; ++k) {
      int i = wv + k * 4;
      if (i < 23) {
        int cb = i * 64 + lane;
        if (cb < 1440) {
          int row = cb / 144, rem = cb % 144;
          gl_lds16((const char*)(xin + (((long)tb[t] * PH + th0[t]) * PW + tw0[t]) * 64) +
                       (long)row * PROWB + rem * 16,
                   smem + boff + cb * 16);
        }
      }
    }
  };

  stage(0, 0);
  asm volatile("" ::: "memory");  // keep stage0 | stage1 issue groups ordered
  stage(1, BUFB);                 // in flight across compute(t0)
  asm volatile("" ::: "memory");
  // own stage0 done: younger ops = own stage1 = 6 loads (wave3: 5), loads-only
  if (wv < 3) asm volatile("s_waitcnt vmcnt(6)" ::: "memory");
  else        asm volatile("s_waitcnt vmcnt(5)" ::: "memory");
  __builtin_amdgcn_sched_barrier(0);

#pragma unroll
  for (int t = 0; t < 2; ++t) {
    const int boff = t * BUFB;
    __builtin_amdgcn_s_barrier();  // all waves' tile-t data landed & visible
    __builtin_amdgcn_sched_barrier(0);

    // ---- MFMA: rows 0..9, rolling 4-slot A window; acc[mf] = out row mf ----
    f32x4 acc[8];
#pragma unroll
    for (int mf = 0; mf < 8; ++mf) acc[mf] = f32x4{0.f, 0.f, 0.f, 0.f};

#pragma unroll
    for (int kw = 0; kw < 3; ++kw)
#pragma unroll
      for (int ks = 0; ks < 2; ++ks) {
        const int col = ol + kw;
        const int sb8 = (ks << 2) | kg;
        bf16x8 a[4];
#pragma unroll
        for (int u = 0; u < 3; ++u) {
          int slot = sb8 ^ ((2 * u + col) & 7);
          a[u] = *reinterpret_cast<const bf16x8*>(smem + boff + (u * 18 + col) * 128 +
                                                  slot * 16);
        }
#pragma unroll
        for (int mf = 0; mf < 8; ++mf) {
          if (mf < 7) {  // row mf+3 into the slot row mf just vacated
            int rr = mf + 3;
            int slot = sb8 ^ ((2 * rr + col) & 7);
            a[(mf + 3) & 3] = *reinterpret_cast<const bf16x8*>(
                smem + boff + (rr * 18 + col) * 128 + slot * 16);
          }
          acc[mf] = __builtin_amdgcn_mfma_f32_16x16x32_bf16(a[mf & 3], wf[0][kw][ks],
                                                            acc[mf], 0, 0, 0);
          acc[mf] = __builtin_amdgcn_mfma_f32_16x16x32_bf16(a[(mf + 1) & 3], wf[1][kw][ks],
                                                            acc[mf], 0, 0, 0);
          acc[mf] = __builtin_amdgcn_mfma_f32_16x16x32_bf16(a[(mf + 2) & 3], wf[2][kw][ks],
                                                            acc[mf], 0, 0, 0);
        }
      }

    if (t == 0) {
      // drain stage1 (loads-only window; latency covered by compute above)
      asm volatile("s_waitcnt vmcnt(0)" ::: "memory");
      __builtin_amdgcn_sched_barrier(0);
    }

    // ---- epilogue ----
    if constexpr (PASS == 0) {
      __builtin_amdgcn_sched_barrier(0);
      __builtin_amdgcn_s_barrier();  // all waves done reading buf[t]: reuse it
      __builtin_amdgcn_sched_barrier(0);
      u16* ys = reinterpret_cast<u16*>(smem + boff);  // [128 px][72]
#pragma unroll
      for (int mf = 0; mf < 8; ++mf)
#pragma unroll
        for (int rg = 0; rg < 4; ++rg) {
          int p = mf * 16 + kg * 4 + rg;
          ys[p * 72 + o] = f2b(fmaxf(acc[mf][rg] * inv + bias, 0.f));
        }
      asm volatile("s_waitcnt lgkmcnt(0)" ::: "memory");
      __builtin_amdgcn_sched_barrier(0);
      __builtin_amdgcn_s_barrier();
      __builtin_amdgcn_sched_barrier(0);
#pragma unroll
      for (int it = 0; it < 4; ++it) {
        int cidx = it * 256 + tid;  // 1024 chunks
        int c8 = cidx & 7, p = cidx >> 3;
        int hp = th0[t] + (p >> 4) + 1, wp = tw0[t] + (p & 15) + 1;
        int gkey = (2 * hp + wp) & 7;
        *reinterpret_cast<u16x8*>(ypad + (((long)tb[t] * PH + hp) * PW + wp) * 64 +
                                  ((c8 ^ gkey) * 8)) =
            *reinterpret_cast<const u16x8*>(ys + p * 72 + c8 * 8);
      }
    } else {
      // direct: acc[mf] row rg = pixel (th0+mf, tw0+kg*4+rg), channel o
#pragma unroll
      for (int half = 0; half < 2; ++half) {
        f32x4 xr[4];
        if constexpr (RESID == 0) {
#pragma unroll
          for (int m = 0; m < 4; ++m) {
            int h = th0[t] + half * 4 + m;
            xr[m] = *reinterpret_cast<const f32x4*>(
                x + (((tb[t] * 64 + o) * NH + h) * NW + tw0[t] + kg * 4));
          }
        } else {
          // bf16 residual from chunk-swizzled xpad (pixel base + slot decode)
#pragma unroll
          for (int m = 0; m < 4; ++m) {
            int hp = th0[t] + half * 4 + m + 1;
#pragma unroll
            for (int rg = 0; rg < 4; ++rg) {
              int wp = tw0[t] + kg * 4 + rg + 1;
              int key = (2 * hp + wp) & 7;
              u16 bv = xres[(((long)tb[t] * PH + hp) * PW + wp) * 64 +
                            ((o >> 3) ^ key) * 8 + (o & 7)];
              xr[m][rg] = b2f(bv);
            }
          }
        }
#pragma unroll
        for (int m = 0; m < 4; ++m) {
          int mf = half * 4 + m;
          int h = th0[t] + mf;
          f32x4 vv;
#pragma unroll
          for (int rg = 0; rg < 4; ++rg)
            vv[rg] = fmaxf(acc[mf][rg] * inv + bias + xr[m][rg], 0.f);
          *reinterpret_cast<f32x4*>(
              out + (((tb[t] * 64 + o) * NH + h) * NW + tw0[t] + kg * 4)) = vv;
        }
      }
    }
  }
}

// ---------------------------------------------------------------------------
extern "C" void kernel_launch(void* const* d_in, const int* in_sizes, int n_in,
                              void* d_out, int out_size, void* d_ws, size_t ws_size,
                              hipStream_t stream) {
  const float* x = (const float*)d_in[0];
  const float* w1 = (const float*)d_in[1];
  const float* w2 = (const float*)d_in[2];
  const float* alpha = (const float*)d_in[3];
  const float* g1 = (const float*)d_in[4];
  const float* b1 = (const float*)d_in[5];
  const float* m1 = (const float*)d_in[6];
  const float* v1 = (const float*)d_in[7];
  const float* g2 = (const float*)d_in[8];
  const float* b2 = (const float*)d_in[9];
  const float* m2 = (const float*)d_in[10];
  const float* v2 = (const float*)d_in[11];
  float* out = (float*)d_out;

  char* ws = (char*)d_ws;
  u16* weff1 = (u16*)ws;                 // 73728 B
  u16* weff2 = (u16*)(ws + 73728);       // 73728 B
  float* bnc = (float*)(ws + 147456);    // 1024 B
  u16* y1pad = (u16*)(ws + 148480);      // 53231616 B
  const size_t PADB = 53231616ull;       // 32*114*114*64*2
  bool big = ws_size >= 148480ull + 2ull * PADB;
  // big ws: xpad in ws (stays live through P1 -> bf16 residual source).
  // small ws: xpad in d_out (dead before P1 writes) -> fp32-x residual (R14).
  u16* xpad = big ? (u16*)(ws + 148480 + PADB) : (u16*)d_out;

  border_zero<<<904, 256, 0, stream>>>(xpad, y1pad);
  transform_kernel<<<32 * NH, 256, 0, stream>>>(x, xpad);
  prep_kernel<<<144, 256, 0, stream>>>(w1, w2, alpha, g1, b1, m1, v1,
                                       g2, b2, m2, v2, weff1, weff2, bnc);
  conv_bn_kernel<0, 0><<<1568, 256, 0, stream>>>(xpad, x, nullptr, weff1, bnc,
                                                 y1pad, nullptr);
  if (big)
    conv_bn_kernel<1, 1><<<1568, 256, 0, stream>>>(y1pad, x, xpad, weff2, bnc,
                                                   nullptr, out);
  else
    conv_bn_kernel<1, 0><<<1568, 256, 0, stream>>>(y1pad, x, nullptr, weff2, bnc,
                                                   nullptr, out);
}

// Round 16
// 133.867 us; speedup vs baseline: 5.2726x; 1.0034x over previous
//
#include <hip/hip_runtime.h>

// BasicBlock: y = relu(bn2(conv2(relu(bn1(conv1(x, we1))), we2)) + x)
// we{1,2} = sum_e alpha[e]*w{1,2}[e].
//
// bf16 implicit-GEMM conv, mfma_f32_16x16x32_bf16, staged from padded,
// chunk-swizzled NHWC bf16 images (slot = c8 ^ ((2h+w)&7) within 128B px).
//
// R16 = R15 (134.3us: 8Mx1N wave remap, bf16 residual) with PASS1 deepened:
// 4 tiles/block (grid 784), residual tile STAGED INTO LDS alongside the y1
// window (epilogue = pure ds_read, no VMEM loads) so stage(t+2), issued
// after the epilogue barrier, stays in flight across compute(t+1) -> 75%
// stage duty (was 50%). Counted gates: stage = 10|9 insts/wave; t<2 gate
// vmcnt(10|9) drains stage(t+1) while leaving stage(t+2) outstanding;
// t=2 gate vmcnt(0). PASS0 unchanged from R15 (healthy at ~48us).

typedef __bf16 bf16x8 __attribute__((ext_vector_type(8)));
typedef float f32x4 __attribute__((ext_vector_type(4)));
typedef unsigned short u16;
typedef u16 u16x8 __attribute__((ext_vector_type(8)));

#define NH 112
#define NW 112
#define PH 114
#define PW 114
#define PROWB (PW * 128)  // 14592 bytes per padded NHWC row
#define BUFB 23040        // y1/x window buffer: 10 rows * 18 px * 128 B

#define WAITVM(n) asm volatile("s_waitcnt vmcnt(" #n ")" ::: "memory")
#define SCHEDB __builtin_amdgcn_sched_barrier(0)

__device__ __forceinline__ u16 f2b(float f) {
  unsigned u = __builtin_bit_cast(unsigned, f);
  u += 0x7FFFu + ((u >> 16) & 1u);
  return (u16)(u >> 16);
}
__device__ __forceinline__ float b2f(u16 b) {
  unsigned u = ((unsigned)b) << 16;
  return __builtin_bit_cast(float, u);
}

__device__ __forceinline__ void gl_lds16(const void* g, void* l) {
  __builtin_amdgcn_global_load_lds(
      (const __attribute__((address_space(1))) unsigned int*)g,
      (__attribute__((address_space(3))) unsigned int*)l, 16, 0, 0);
}

// ---------------------------------------------------------------------------
__global__ void border_zero(u16* __restrict__ a, u16* __restrict__ bbuf) {
  int idx = blockIdx.x * 256 + threadIdx.x;  // 2*32*452*8 = 231424 chunks
  if (idx >= 231424) return;
  int c8 = idx & 7;
  int t = idx >> 3;
  int buf = t >= 14464;
  t -= buf * 14464;
  int img = t / 452, e = t % 452;
  int h, w;
  if (e < 114) { h = 0; w = e; }
  else if (e < 228) { h = 113; w = e - 114; }
  else if (e < 340) { h = e - 227; w = 0; }
  else { h = e - 339; w = 113; }
  u16* base = buf ? bbuf : a;
  u16x8 z = {0, 0, 0, 0, 0, 0, 0, 0};
  *reinterpret_cast<u16x8*>(base + (((long)img * PH + h) * PW + w) * 64 + c8 * 8) = z;
}

// ---------------------------------------------------------------------------
// x NCHW fp32 -> x_pad NHWC bf16 (padded + chunk-swizzled). block = (b,h).
__global__ __launch_bounds__(256) void transform_kernel(const float* __restrict__ x,
                                                        u16* __restrict__ xpad) {
  __shared__ alignas(16) u16 t[7168];  // [112 px][64 ch], xor-swizzled bytes
  int tid = threadIdx.x, bid = blockIdx.x;
  int b = bid / NH, h = bid % NH;
  const float* src = x + (long)b * 64 * 12544 + h * NW;
  f32x4 v[7];
#pragma unroll
  for (int it = 0; it < 7; ++it) {
    int fid = it * 256 + tid;  // 1792 = 64 ch * 28 quads
    int c = fid / 28, wq = fid % 28;
    v[it] = *reinterpret_cast<const f32x4*>(src + c * 12544 + wq * 4);
  }
#pragma unroll
  for (int it = 0; it < 7; ++it) {
    int fid = it * 256 + tid;
    int c = fid / 28, wq = fid % 28;
    int key = (wq & 7) << 4;
#pragma unroll
    for (int j = 0; j < 4; ++j) {
      int px = wq * 4 + j;
      *reinterpret_cast<u16*>((char*)t + px * 128 + ((c * 2) ^ key)) = f2b(v[it][j]);
    }
  }
  __syncthreads();
  int hp = h + 1;
  u16* rowb = xpad + (((long)b * PH + hp) * PW) * 64;
#pragma unroll
  for (int it = 0; it < 4; ++it) {
    int cidx = it * 256 + tid;
    if (cidx < 896) {  // 112 px * 8 chunks
      int c8 = cidx & 7, px = cidx >> 3;
      int lchunk = c8 ^ ((px >> 2) & 7);
      u16x8 vv = *reinterpret_cast<const u16x8*>((const char*)t + px * 128 + lchunk * 16);
      int wp = px + 1;
      int gkey = (2 * hp + wp) & 7;
      *reinterpret_cast<u16x8*>(rowb + (long)wp * 64 + ((c8 ^ gkey) * 8)) = vv;
    }
  }
}

// ---------------------------------------------------------------------------
// fold experts -> w_eff bf16 [kpos][o][i] + folded BN constants
__global__ void prep_kernel(
    const float* __restrict__ w1, const float* __restrict__ w2,
    const float* __restrict__ alpha,
    const float* __restrict__ g1, const float* __restrict__ b1,
    const float* __restrict__ m1, const float* __restrict__ v1,
    const float* __restrict__ g2, const float* __restrict__ b2,
    const float* __restrict__ m2, const float* __restrict__ v2,
    u16* __restrict__ weff1, u16* __restrict__ weff2, float* __restrict__ bnc) {
  int idx = blockIdx.x * 256 + threadIdx.x;  // 36864
  if (idx < 36864) {
    int i = idx & 63;
    int o = (idx >> 6) & 63;
    int kpos = idx >> 12;
    int base = (o * 64 + i) * 9 + kpos;  // src [E][O][I][3][3]
    float a1 = 0.f, a2 = 0.f;
#pragma unroll
    for (int e = 0; e < 10; ++e) {
      float al = alpha[e];
      a1 += al * w1[e * 36864 + base];
      a2 += al * w2[e * 36864 + base];
    }
    weff1[idx] = f2b(a1);
    weff2[idx] = f2b(a2);
  }
  if (blockIdx.x == 0 && threadIdx.x < 64) {
    int c = threadIdx.x;
    float i1 = g1[c] * rsqrtf(v1[c] + 1e-5f);
    float i2 = g2[c] * rsqrtf(v2[c] + 1e-5f);
    bnc[c] = i1;
    bnc[64 + c] = b1[c] - m1[c] * i1;
    bnc[128 + c] = i2;
    bnc[192 + c] = b2[c] - m2[c] * i2;
  }
}

// ---------------------------------------------------------------------------
// PASS 0 (unchanged from R15): 8x16 px x 64 oc, 2 tiles/block, grid 1568.
// x_pad -> bn1+relu -> y1_pad (swizzled NHWC bf16)
// ---------------------------------------------------------------------------
__global__ __launch_bounds__(256, 2) void conv_p0_kernel(
    const u16* __restrict__ xin, const u16* __restrict__ weff,
    const float* __restrict__ bnc, u16* __restrict__ ypad) {
  __shared__ alignas(64) char smem[2 * BUFB];

  int tid = threadIdx.x, lane = tid & 63, wv = tid >> 6;
  int ol = lane & 15, kg = (lane >> 4) & 3;
  const int o = wv * 16 + ol;

  float inv = bnc[o];
  float bias = bnc[64 + o];

  bf16x8 wf[3][3][2];  // 18 frags = 72 VGPR
#pragma unroll
  for (int kh = 0; kh < 3; ++kh)
#pragma unroll
    for (int kw = 0; kw < 3; ++kw)
#pragma unroll
      for (int ks = 0; ks < 2; ++ks)
        wf[kh][kw][ks] = __builtin_bit_cast(
            bf16x8, *reinterpret_cast<const u16x8*>(
                        weff + (((kh * 3 + kw) * 64 + o) * 64 + ks * 32 + kg * 8)));
  asm volatile("s_waitcnt vmcnt(0)" ::: "memory");
  SCHEDB;

  int sb = (blockIdx.x & 7) * 196 + (blockIdx.x >> 3);
  int tb[2], th0[2], tw0[2];
#pragma unroll
  for (int t = 0; t < 2; ++t) {
    int tt = sb * 2 + t;
    tb[t] = tt / 98;
    int r = tt % 98;
    th0[t] = (r / 7) * 8;
    tw0[t] = (r % 7) * 16;
  }

  auto stage = [&](int t, int boff) {
#pragma unroll
    for (int k = 0; k < 6; ++k) {
      int i = wv + k * 4;
      if (i < 23) {
        int cb = i * 64 + lane;
        if (cb < 1440) {
          int row = cb / 144, rem = cb % 144;
          gl_lds16((const char*)(xin + (((long)tb[t] * PH + th0[t]) * PW + tw0[t]) * 64) +
                       (long)row * PROWB + rem * 16,
                   smem + boff + cb * 16);
        }
      }
    }
  };

  stage(0, 0);
  asm volatile("" ::: "memory");
  stage(1, BUFB);
  asm volatile("" ::: "memory");
  if (wv < 3) WAITVM(6);
  else        WAITVM(5);
  SCHEDB;

#pragma unroll
  for (int t = 0; t < 2; ++t) {
    const int boff = t * BUFB;
    __builtin_amdgcn_s_barrier();
    SCHEDB;

    f32x4 acc[8];
#pragma unroll
    for (int mf = 0; mf < 8; ++mf) acc[mf] = f32x4{0.f, 0.f, 0.f, 0.f};

#pragma unroll
    for (int kw = 0; kw < 3; ++kw)
#pragma unroll
      for (int ks = 0; ks < 2; ++ks) {
        const int col = ol + kw;
        const int sb8 = (ks << 2) | kg;
        bf16x8 a[4];
#pragma unroll
        for (int u = 0; u < 3; ++u) {
          int slot = sb8 ^ ((2 * u + col) & 7);
          a[u] = *reinterpret_cast<const bf16x8*>(smem + boff + (u * 18 + col) * 128 +
                                                  slot * 16);
        }
#pragma unroll
        for (int mf = 0; mf < 8; ++mf) {
          if (mf < 7) {
            int rr = mf + 3;
            int slot = sb8 ^ ((2 * rr + col) & 7);
            a[(mf + 3) & 3] = *reinterpret_cast<const bf16x8*>(
                smem + boff + (rr * 18 + col) * 128 + slot * 16);
          }
          acc[mf] = __builtin_amdgcn_mfma_f32_16x16x32_bf16(a[mf & 3], wf[0][kw][ks],
                                                            acc[mf], 0, 0, 0);
          acc[mf] = __builtin_amdgcn_mfma_f32_16x16x32_bf16(a[(mf + 1) & 3], wf[1][kw][ks],
                                                            acc[mf], 0, 0, 0);
          acc[mf] = __builtin_amdgcn_mfma_f32_16x16x32_bf16(a[(mf + 2) & 3], wf[2][kw][ks],
                                                            acc[mf], 0, 0, 0);
        }
      }

    if (t == 0) {
      asm volatile("s_waitcnt vmcnt(0)" ::: "memory");
      SCHEDB;
    }

    SCHEDB;
    __builtin_amdgcn_s_barrier();  // all waves done reading buf[t]: reuse it
    SCHEDB;
    u16* ys = reinterpret_cast<u16*>(smem + boff);  // [128 px][72]
#pragma unroll
    for (int mf = 0; mf < 8; ++mf)
#pragma unroll
      for (int rg = 0; rg < 4; ++rg) {
        int p = mf * 16 + kg * 4 + rg;
        ys[p * 72 + o] = f2b(fmaxf(acc[mf][rg] * inv + bias, 0.f));
      }
    asm volatile("s_waitcnt lgkmcnt(0)" ::: "memory");
    SCHEDB;
    __builtin_amdgcn_s_barrier();
    SCHEDB;
#pragma unroll
    for (int it = 0; it < 4; ++it) {
      int cidx = it * 256 + tid;  // 1024 chunks
      int c8 = cidx & 7, p = cidx >> 3;
      int hp = th0[t] + (p >> 4) + 1, wp = tw0[t] + (p & 15) + 1;
      int gkey = (2 * hp + wp) & 7;
      *reinterpret_cast<u16x8*>(ypad + (((long)tb[t] * PH + hp) * PW + wp) * 64 +
                                ((c8 ^ gkey) * 8)) =
          *reinterpret_cast<const u16x8*>(ys + p * 72 + c8 * 8);
    }
  }
}

// ---------------------------------------------------------------------------
// PASS 1: 4 tiles/block over 2 LDS buffers, grid 784 (= 8*98 XCD-bijective).
// Per buffer: [y1 window 23040 B][residual tile 16384 B] (RESID=1).
// y1_pad -> bn2 + residual + relu -> out. Epilogue has ZERO VMEM loads
// (residual via ds_read), so stage(t+2) stays in flight across compute(t+1).
// ---------------------------------------------------------------------------
template <int RESID>
__global__ __launch_bounds__(256, 2) void conv_p1_kernel(
    const u16* __restrict__ yin, const float* __restrict__ x,
    const u16* __restrict__ xres, const u16* __restrict__ weff,
    const float* __restrict__ bnc, float* __restrict__ out) {
  constexpr int BUF = RESID ? (BUFB + 16384) : BUFB;
  __shared__ alignas(64) char smem[2 * BUF];

  int tid = threadIdx.x, lane = tid & 63, wv = tid >> 6;
  int ol = lane & 15, kg = (lane >> 4) & 3;
  const int o = wv * 16 + ol;

  float inv = bnc[128 + o];
  float bias = bnc[192 + o];

  bf16x8 wf[3][3][2];
#pragma unroll
  for (int kh = 0; kh < 3; ++kh)
#pragma unroll
    for (int kw = 0; kw < 3; ++kw)
#pragma unroll
      for (int ks = 0; ks < 2; ++ks)
        wf[kh][kw][ks] = __builtin_bit_cast(
            bf16x8, *reinterpret_cast<const u16x8*>(
                        weff + (((kh * 3 + kw) * 64 + o) * 64 + ks * 32 + kg * 8)));
  asm volatile("s_waitcnt vmcnt(0)" ::: "memory");
  SCHEDB;

  int sb = (blockIdx.x & 7) * 98 + (blockIdx.x >> 3);
  int tb[4], th0[4], tw0[4];
#pragma unroll
  for (int t = 0; t < 4; ++t) {
    int tt = sb * 4 + t;
    tb[t] = tt / 98;
    int r = tt % 98;
    th0[t] = (r / 7) * 8;
    tw0[t] = (r % 7) * 16;
  }

  // stage: y1 window (1440 chunks; 6,6,6,5 insts) + residual tile
  // (1024 chunks; 4,4,4,4 insts) -> per-wave totals 10,10,10,9
  auto stage = [&](int t, int boff) {
#pragma unroll
    for (int k = 0; k < 6; ++k) {
      int i = wv + k * 4;
      if (i < 23) {
        int cb = i * 64 + lane;
        if (cb < 1440) {
          int row = cb / 144, rem = cb % 144;
          gl_lds16((const char*)(yin + (((long)tb[t] * PH + th0[t]) * PW + tw0[t]) * 64) +
                       (long)row * PROWB + rem * 16,
                   smem + boff + cb * 16);
        }
      }
    }
    if constexpr (RESID) {
#pragma unroll
      for (int k = 0; k < 4; ++k) {
        int i = wv + k * 4;  // 0..15
        int cr = i * 64 + lane;
        int rp = cr >> 7, rem = cr & 127;
        gl_lds16((const char*)xres +
                     (((long)tb[t] * PH + th0[t] + 1 + rp) * PW + tw0[t] + 1) * 128 +
                     rem * 16,
                 smem + boff + BUFB + cr * 16);
      }
    }
  };
  auto gateS = [&] {
    if constexpr (RESID) {
      if (wv < 3) WAITVM(10); else WAITVM(9);
    } else {
      if (wv < 3) WAITVM(6); else WAITVM(5);
    }
  };

  stage(0, 0);
  asm volatile("" ::: "memory");
  stage(1, BUF);
  asm volatile("" ::: "memory");
  gateS();
  SCHEDB;

#pragma unroll
  for (int t = 0; t < 4; ++t) {
    const int boff = (t & 1) * BUF;
    __builtin_amdgcn_s_barrier();  // stage(t) landed & visible to all waves
    SCHEDB;

    f32x4 acc[8];
#pragma unroll
    for (int mf = 0; mf < 8; ++mf) acc[mf] = f32x4{0.f, 0.f, 0.f, 0.f};

#pragma unroll
    for (int kw = 0; kw < 3; ++kw)
#pragma unroll
      for (int ks = 0; ks < 2; ++ks) {
        const int col = ol + kw;
        const int sb8 = (ks << 2) | kg;
        bf16x8 a[4];
#pragma unroll
        for (int u = 0; u < 3; ++u) {
          int slot = sb8 ^ ((2 * u + col) & 7);
          a[u] = *reinterpret_cast<const bf16x8*>(smem + boff + (u * 18 + col) * 128 +
                                                  slot * 16);
        }
#pragma unroll
        for (int mf = 0; mf < 8; ++mf) {
          if (mf < 7) {
            int rr = mf + 3;
            int slot = sb8 ^ ((2 * rr + col) & 7);
            a[(mf + 3) & 3] = *reinterpret_cast<const bf16x8*>(
                smem + boff + (rr * 18 + col) * 128 + slot * 16);
          }
          acc[mf] = __builtin_amdgcn_mfma_f32_16x16x32_bf16(a[mf & 3], wf[0][kw][ks],
                                                            acc[mf], 0, 0, 0);
          acc[mf] = __builtin_amdgcn_mfma_f32_16x16x32_bf16(a[(mf + 1) & 3], wf[1][kw][ks],
                                                            acc[mf], 0, 0, 0);
          acc[mf] = __builtin_amdgcn_mfma_f32_16x16x32_bf16(a[(mf + 2) & 3], wf[2][kw][ks],
                                                            acc[mf], 0, 0, 0);
        }
      }

    // ---- epilogue: bn2 + residual + relu -> direct NCHW f32x4 stores ----
    if constexpr (RESID) {
      // residual from the LDS-staged tile: zero VMEM loads here
#pragma unroll
      for (int mf = 0; mf < 8; ++mf) {
        int h = th0[t] + mf, hp = h + 1;
        f32x4 vv;
#pragma unroll
        for (int rg = 0; rg < 4; ++rg) {
          int wq = kg * 4 + rg, wp = tw0[t] + wq + 1;
          int key = (2 * hp + wp) & 7;
          u16 bv = *reinterpret_cast<const u16*>(
              smem + boff + BUFB + (mf * 16 + wq) * 128 + (((o >> 3) ^ key) * 16) +
              (o & 7) * 2);
          vv[rg] = fmaxf(acc[mf][rg] * inv + bias + b2f(bv), 0.f);
        }
        *reinterpret_cast<f32x4*>(out + (((tb[t] * 64 + o) * NH + h) * NW + tw0[t] +
                                         kg * 4)) = vv;
      }
    } else {
#pragma unroll
      for (int half = 0; half < 2; ++half) {
        f32x4 xr[4];
#pragma unroll
        for (int m = 0; m < 4; ++m) {
          int h = th0[t] + half * 4 + m;
          xr[m] = *reinterpret_cast<const f32x4*>(
              x + (((tb[t] * 64 + o) * NH + h) * NW + tw0[t] + kg * 4));
        }
#pragma unroll
        for (int m = 0; m < 4; ++m) {
          int mf = half * 4 + m;
          int h = th0[t] + mf;
          f32x4 vv;
#pragma unroll
          for (int rg = 0; rg < 4; ++rg)
            vv[rg] = fmaxf(acc[mf][rg] * inv + bias + xr[m][rg], 0.f);
          *reinterpret_cast<f32x4*>(
              out + (((tb[t] * 64 + o) * NH + h) * NW + tw0[t] + kg * 4)) = vv;
        }
      }
    }

    SCHEDB;
    __builtin_amdgcn_s_barrier();  // all waves done reading buf_t (y1 + res)
    SCHEDB;
    if (t + 2 < 4) stage(t + 2, boff);
    if (t < 2) {
      gateS();  // stage(t+1) done; stage(t+2) stays outstanding
    } else if (t == 2) {
      WAITVM(0);  // stage(3) done (covered by compute(2)+epilogue(2))
    }
    SCHEDB;
  }
}

// ---------------------------------------------------------------------------
extern "C" void kernel_launch(void* const* d_in, const int* in_sizes, int n_in,
                              void* d_out, int out_size, void* d_ws, size_t ws_size,
                              hipStream_t stream) {
  const float* x = (const float*)d_in[0];
  const float* w1 = (const float*)d_in[1];
  const float* w2 = (const float*)d_in[2];
  const float* alpha = (const float*)d_in[3];
  const float* g1 = (const float*)d_in[4];
  const float* b1 = (const float*)d_in[5];
  const float* m1 = (const float*)d_in[6];
  const float* v1 = (const float*)d_in[7];
  const float* g2 = (const float*)d_in[8];
  const float* b2 = (const float*)d_in[9];
  const float* m2 = (const float*)d_in[10];
  const float* v2 = (const float*)d_in[11];
  float* out = (float*)d_out;

  char* ws = (char*)d_ws;
  u16* weff1 = (u16*)ws;                 // 73728 B
  u16* weff2 = (u16*)(ws + 73728);       // 73728 B
  float* bnc = (float*)(ws + 147456);    // 1024 B
  u16* y1pad = (u16*)(ws + 148480);      // 53231616 B
  const size_t PADB = 53231616ull;       // 32*114*114*64*2
  bool big = ws_size >= 148480ull + 2ull * PADB;
  // big ws: xpad in ws (stays live through P1 -> bf16 residual source).
  // small ws: xpad in d_out (dead before P1 writes) -> fp32-x residual.
  u16* xpad = big ? (u16*)(ws + 148480 + PADB) : (u16*)d_out;

  border_zero<<<904, 256, 0, stream>>>(xpad, y1pad);
  transform_kernel<<<32 * NH, 256, 0, stream>>>(x, xpad);
  prep_kernel<<<144, 256, 0, stream>>>(w1, w2, alpha, g1, b1, m1, v1,
                                       g2, b2, m2, v2, weff1, weff2, bnc);
  conv_p0_kernel<<<1568, 256, 0, stream>>>(xpad, weff1, bnc, y1pad);
  if (big)
    conv_p1_kernel<1><<<784, 256, 0, stream>>>(y1pad, x, xpad, weff2, bnc, out);
  else
    conv_p1_kernel<0><<<784, 256, 0, stream>>>(y1pad, x, nullptr, weff2, bnc, out);
}

// Round 17
// 119.302 us; speedup vs baseline: 5.9163x; 1.1221x over previous
//
#include <hip/hip_runtime.h>

// BasicBlock: y = relu(bn2(conv2(relu(bn1(conv1(x, we1))), we2)) + x)
// we{1,2} = sum_e alpha[e]*w{1,2}[e].
//
// bf16 implicit-GEMM conv, mfma_f32_16x16x32_bf16, staged from padded,
// chunk-swizzled NHWC bf16 images (slot = c8 ^ ((2h+w)&7) within 128B px).
//
// R17: PERSISTENT conv blocks. R16's 4-tile pipeline was cancelled by
// grid-tail (784 blocks / 512 concurrent = 1.53 rounds -> 47% idle round).
// Now grid = 512 exactly (2 blocks/CU); each block walks tiles sb + 512*j
// (n = 6 or 7) with rolling 2-buffer LDS; stage(j+2) issued in epilogue(j)
// -> every compute covered, zero scheduling tail. P1 keeps the LDS-staged
// bf16 residual (epilogue has no VMEM loads -> prefetch survives).
// Counted gates (loads-only sound): P0 vmcnt(6|5), P1 vmcnt(10|9).

typedef __bf16 bf16x8 __attribute__((ext_vector_type(8)));
typedef float f32x4 __attribute__((ext_vector_type(4)));
typedef unsigned short u16;
typedef u16 u16x8 __attribute__((ext_vector_type(8)));

#define NH 112
#define NW 112
#define PH 114
#define PW 114
#define PROWB (PW * 128)  // 14592 bytes per padded NHWC row
#define BUFB 23040        // y1/x window buffer: 10 rows * 18 px * 128 B
#define NTILES 3136       // 32 images * 98 tiles

#define WAITVM(n) asm volatile("s_waitcnt vmcnt(" #n ")" ::: "memory")
#define SCHEDB __builtin_amdgcn_sched_barrier(0)

__device__ __forceinline__ u16 f2b(float f) {
  unsigned u = __builtin_bit_cast(unsigned, f);
  u += 0x7FFFu + ((u >> 16) & 1u);
  return (u16)(u >> 16);
}
__device__ __forceinline__ float b2f(u16 b) {
  unsigned u = ((unsigned)b) << 16;
  return __builtin_bit_cast(float, u);
}

__device__ __forceinline__ void gl_lds16(const void* g, void* l) {
  __builtin_amdgcn_global_load_lds(
      (const __attribute__((address_space(1))) unsigned int*)g,
      (__attribute__((address_space(3))) unsigned int*)l, 16, 0, 0);
}

// ---------------------------------------------------------------------------
__global__ void border_zero(u16* __restrict__ a, u16* __restrict__ bbuf) {
  int idx = blockIdx.x * 256 + threadIdx.x;  // 2*32*452*8 = 231424 chunks
  if (idx >= 231424) return;
  int c8 = idx & 7;
  int t = idx >> 3;
  int buf = t >= 14464;
  t -= buf * 14464;
  int img = t / 452, e = t % 452;
  int h, w;
  if (e < 114) { h = 0; w = e; }
  else if (e < 228) { h = 113; w = e - 114; }
  else if (e < 340) { h = e - 227; w = 0; }
  else { h = e - 339; w = 113; }
  u16* base = buf ? bbuf : a;
  u16x8 z = {0, 0, 0, 0, 0, 0, 0, 0};
  *reinterpret_cast<u16x8*>(base + (((long)img * PH + h) * PW + w) * 64 + c8 * 8) = z;
}

// ---------------------------------------------------------------------------
// x NCHW fp32 -> x_pad NHWC bf16 (padded + chunk-swizzled). block = (b,h).
__global__ __launch_bounds__(256) void transform_kernel(const float* __restrict__ x,
                                                        u16* __restrict__ xpad) {
  __shared__ alignas(16) u16 t[7168];  // [112 px][64 ch], xor-swizzled bytes
  int tid = threadIdx.x, bid = blockIdx.x;
  int b = bid / NH, h = bid % NH;
  const float* src = x + (long)b * 64 * 12544 + h * NW;
  f32x4 v[7];
#pragma unroll
  for (int it = 0; it < 7; ++it) {
    int fid = it * 256 + tid;  // 1792 = 64 ch * 28 quads
    int c = fid / 28, wq = fid % 28;
    v[it] = *reinterpret_cast<const f32x4*>(src + c * 12544 + wq * 4);
  }
#pragma unroll
  for (int it = 0; it < 7; ++it) {
    int fid = it * 256 + tid;
    int c = fid / 28, wq = fid % 28;
    int key = (wq & 7) << 4;
#pragma unroll
    for (int j = 0; j < 4; ++j) {
      int px = wq * 4 + j;
      *reinterpret_cast<u16*>((char*)t + px * 128 + ((c * 2) ^ key)) = f2b(v[it][j]);
    }
  }
  __syncthreads();
  int hp = h + 1;
  u16* rowb = xpad + (((long)b * PH + hp) * PW) * 64;
#pragma unroll
  for (int it = 0; it < 4; ++it) {
    int cidx = it * 256 + tid;
    if (cidx < 896) {  // 112 px * 8 chunks
      int c8 = cidx & 7, px = cidx >> 3;
      int lchunk = c8 ^ ((px >> 2) & 7);
      u16x8 vv = *reinterpret_cast<const u16x8*>((const char*)t + px * 128 + lchunk * 16);
      int wp = px + 1;
      int gkey = (2 * hp + wp) & 7;
      *reinterpret_cast<u16x8*>(rowb + (long)wp * 64 + ((c8 ^ gkey) * 8)) = vv;
    }
  }
}

// ---------------------------------------------------------------------------
// fold experts -> w_eff bf16 [kpos][o][i] + folded BN constants
__global__ void prep_kernel(
    const float* __restrict__ w1, const float* __restrict__ w2,
    const float* __restrict__ alpha,
    const float* __restrict__ g1, const float* __restrict__ b1,
    const float* __restrict__ m1, const float* __restrict__ v1,
    const float* __restrict__ g2, const float* __restrict__ b2,
    const float* __restrict__ m2, const float* __restrict__ v2,
    u16* __restrict__ weff1, u16* __restrict__ weff2, float* __restrict__ bnc) {
  int idx = blockIdx.x * 256 + threadIdx.x;  // 36864
  if (idx < 36864) {
    int i = idx & 63;
    int o = (idx >> 6) & 63;
    int kpos = idx >> 12;
    int base = (o * 64 + i) * 9 + kpos;  // src [E][O][I][3][3]
    float a1 = 0.f, a2 = 0.f;
#pragma unroll
    for (int e = 0; e < 10; ++e) {
      float al = alpha[e];
      a1 += al * w1[e * 36864 + base];
      a2 += al * w2[e * 36864 + base];
    }
    weff1[idx] = f2b(a1);
    weff2[idx] = f2b(a2);
  }
  if (blockIdx.x == 0 && threadIdx.x < 64) {
    int c = threadIdx.x;
    float i1 = g1[c] * rsqrtf(v1[c] + 1e-5f);
    float i2 = g2[c] * rsqrtf(v2[c] + 1e-5f);
    bnc[c] = i1;
    bnc[64 + c] = b1[c] - m1[c] * i1;
    bnc[128 + c] = i2;
    bnc[192 + c] = b2[c] - m2[c] * i2;
  }
}

// ---------------------------------------------------------------------------
// PASS 0 (persistent): grid 512, block walks tiles sb + 512*j (n = 6|7).
// x_pad -> bn1+relu -> y1_pad (swizzled NHWC bf16)
// ---------------------------------------------------------------------------
__global__ __launch_bounds__(256, 2) void conv_p0_kernel(
    const u16* __restrict__ xin, const u16* __restrict__ weff,
    const float* __restrict__ bnc, u16* __restrict__ ypad) {
  __shared__ alignas(64) char smem[2 * BUFB];

  int tid = threadIdx.x, lane = tid & 63, wv = tid >> 6;
  int ol = lane & 15, kg = (lane >> 4) & 3;
  const int o = wv * 16 + ol;

  float inv = bnc[o];
  float bias = bnc[64 + o];

  bf16x8 wf[3][3][2];  // 18 frags = 72 VGPR
#pragma unroll
  for (int kh = 0; kh < 3; ++kh)
#pragma unroll
    for (int kw = 0; kw < 3; ++kw)
#pragma unroll
      for (int ks = 0; ks < 2; ++ks)
        wf[kh][kw][ks] = __builtin_bit_cast(
            bf16x8, *reinterpret_cast<const u16x8*>(
                        weff + (((kh * 3 + kw) * 64 + o) * 64 + ks * 32 + kg * 8)));
  asm volatile("s_waitcnt vmcnt(0)" ::: "memory");
  SCHEDB;

  const int sb = (blockIdx.x & 7) * 64 + (blockIdx.x >> 3);  // 512 = 8*64
  const int n = (NTILES - sb + 511) >> 9;                    // 6 or 7 tiles

  auto stage = [&](int tt, int boff) {
    int b = tt / 98;
    int r = tt % 98;
    int h0 = (r / 7) * 8, w0 = (r % 7) * 16;
    const char* src = (const char*)(xin + (((long)b * PH + h0) * PW + w0) * 64);
#pragma unroll
    for (int k = 0; k < 6; ++k) {
      int i = wv + k * 4;
      if (i < 23) {
        int cb = i * 64 + lane;
        if (cb < 1440) {
          int row = cb / 144, rem = cb % 144;
          gl_lds16(src + (long)row * PROWB + rem * 16, smem + boff + cb * 16);
        }
      }
    }
  };

  stage(sb, 0);
  asm volatile("" ::: "memory");
  stage(sb + 512, BUFB);
  asm volatile("" ::: "memory");
  if (wv < 3) WAITVM(6);
  else        WAITVM(5);
  SCHEDB;

  for (int j = 0; j < n; ++j) {
    const int boff = (j & 1) * BUFB;
    const int tt = sb + (j << 9);
    const int b = tt / 98;
    const int r = tt % 98;
    const int th0 = (r / 7) * 8, tw0 = (r % 7) * 16;

    __builtin_amdgcn_s_barrier();  // stage(j) landed & visible block-wide
    SCHEDB;

    f32x4 acc[8];
#pragma unroll
    for (int mf = 0; mf < 8; ++mf) acc[mf] = f32x4{0.f, 0.f, 0.f, 0.f};

#pragma unroll
    for (int kw = 0; kw < 3; ++kw)
#pragma unroll
      for (int ks = 0; ks < 2; ++ks) {
        const int col = ol + kw;
        const int sb8 = (ks << 2) | kg;
        bf16x8 a[4];
#pragma unroll
        for (int u = 0; u < 3; ++u) {
          int slot = sb8 ^ ((2 * u + col) & 7);
          a[u] = *reinterpret_cast<const bf16x8*>(smem + boff + (u * 18 + col) * 128 +
                                                  slot * 16);
        }
#pragma unroll
        for (int mf = 0; mf < 8; ++mf) {
          if (mf < 7) {
            int rr = mf + 3;
            int slot = sb8 ^ ((2 * rr + col) & 7);
            a[(mf + 3) & 3] = *reinterpret_cast<const bf16x8*>(
                smem + boff + (rr * 18 + col) * 128 + slot * 16);
          }
          acc[mf] = __builtin_amdgcn_mfma_f32_16x16x32_bf16(a[mf & 3], wf[0][kw][ks],
                                                            acc[mf], 0, 0, 0);
          acc[mf] = __builtin_amdgcn_mfma_f32_16x16x32_bf16(a[(mf + 1) & 3], wf[1][kw][ks],
                                                            acc[mf], 0, 0, 0);
          acc[mf] = __builtin_amdgcn_mfma_f32_16x16x32_bf16(a[(mf + 2) & 3], wf[2][kw][ks],
                                                            acc[mf], 0, 0, 0);
        }
      }

    SCHEDB;
    __builtin_amdgcn_s_barrier();  // all waves done reading buf: reuse as ys
    SCHEDB;
    u16* ys = reinterpret_cast<u16*>(smem + boff);  // [128 px][72]
#pragma unroll
    for (int mf = 0; mf < 8; ++mf)
#pragma unroll
      for (int rg = 0; rg < 4; ++rg) {
        int p = mf * 16 + kg * 4 + rg;
        ys[p * 72 + o] = f2b(fmaxf(acc[mf][rg] * inv + bias, 0.f));
      }
    asm volatile("s_waitcnt lgkmcnt(0)" ::: "memory");
    SCHEDB;
    __builtin_amdgcn_s_barrier();
    SCHEDB;
#pragma unroll
    for (int it = 0; it < 4; ++it) {
      int cidx = it * 256 + tid;  // 1024 chunks
      int c8 = cidx & 7, p = cidx >> 3;
      int hp = th0 + (p >> 4) + 1, wp = tw0 + (p & 15) + 1;
      int gkey = (2 * hp + wp) & 7;
      *reinterpret_cast<u16x8*>(ypad + (((long)b * PH + hp) * PW + wp) * 64 +
                                ((c8 ^ gkey) * 8)) =
          *reinterpret_cast<const u16x8*>(ys + p * 72 + c8 * 8);
    }

    if (j + 1 < n) {
      SCHEDB;
      __builtin_amdgcn_s_barrier();  // ys LDS reads done -> buf restageable
      SCHEDB;
      if (j + 2 < n) {
        stage(sb + ((j + 2) << 9), boff);
        if (wv < 3) WAITVM(6);  // stage(j+1) done; stage(j+2) outstanding
        else        WAITVM(5);
      } else {
        WAITVM(0);  // stage(j+1) done (no further stages)
      }
      SCHEDB;
    }
  }
}

// ---------------------------------------------------------------------------
// PASS 1 (persistent): grid 512, tiles sb + 512*j. Per LDS buffer:
// [y1 window 23040 B][residual tile 16384 B] (RESID=1). Epilogue has ZERO
// VMEM loads (residual via ds_read) -> stage(j+2) survives across compute.
// y1_pad -> bn2 + residual + relu -> out (NCHW f32)
// ---------------------------------------------------------------------------
template <int RESID>
__global__ __launch_bounds__(256, 2) void conv_p1_kernel(
    const u16* __restrict__ yin, const float* __restrict__ x,
    const u16* __restrict__ xres, const u16* __restrict__ weff,
    const float* __restrict__ bnc, float* __restrict__ out) {
  constexpr int BUF = RESID ? (BUFB + 16384) : BUFB;
  __shared__ alignas(64) char smem[2 * BUF];

  int tid = threadIdx.x, lane = tid & 63, wv = tid >> 6;
  int ol = lane & 15, kg = (lane >> 4) & 3;
  const int o = wv * 16 + ol;

  float inv = bnc[128 + o];
  float bias = bnc[192 + o];

  bf16x8 wf[3][3][2];
#pragma unroll
  for (int kh = 0; kh < 3; ++kh)
#pragma unroll
    for (int kw = 0; kw < 3; ++kw)
#pragma unroll
      for (int ks = 0; ks < 2; ++ks)
        wf[kh][kw][ks] = __builtin_bit_cast(
            bf16x8, *reinterpret_cast<const u16x8*>(
                        weff + (((kh * 3 + kw) * 64 + o) * 64 + ks * 32 + kg * 8)));
  asm volatile("s_waitcnt vmcnt(0)" ::: "memory");
  SCHEDB;

  const int sb = (blockIdx.x & 7) * 64 + (blockIdx.x >> 3);
  const int n = (NTILES - sb + 511) >> 9;

  auto stage = [&](int tt, int boff) {
    int b = tt / 98;
    int r = tt % 98;
    int h0 = (r / 7) * 8, w0 = (r % 7) * 16;
    const char* src = (const char*)(yin + (((long)b * PH + h0) * PW + w0) * 64);
#pragma unroll
    for (int k = 0; k < 6; ++k) {
      int i = wv + k * 4;
      if (i < 23) {
        int cb = i * 64 + lane;
        if (cb < 1440) {
          int row = cb / 144, rem = cb % 144;
          gl_lds16(src + (long)row * PROWB + rem * 16, smem + boff + cb * 16);
        }
      }
    }
    if constexpr (RESID) {
#pragma unroll
      for (int k = 0; k < 4; ++k) {
        int i = wv + k * 4;  // 0..15
        int cr = i * 64 + lane;
        int rp = cr >> 7, rem = cr & 127;
        gl_lds16((const char*)xres + (((long)b * PH + h0 + 1 + rp) * PW + w0 + 1) * 128 +
                     rem * 16,
                 smem + boff + BUFB + cr * 16);
      }
    }
  };
  auto gateS = [&] {
    if constexpr (RESID) {
      if (wv < 3) WAITVM(10); else WAITVM(9);
    } else {
      if (wv < 3) WAITVM(6); else WAITVM(5);
    }
  };

  stage(sb, 0);
  asm volatile("" ::: "memory");
  stage(sb + 512, BUF);
  asm volatile("" ::: "memory");
  gateS();
  SCHEDB;

  for (int j = 0; j < n; ++j) {
    const int boff = (j & 1) * BUF;
    const int tt = sb + (j << 9);
    const int b = tt / 98;
    const int r = tt % 98;
    const int th0 = (r / 7) * 8, tw0 = (r % 7) * 16;

    __builtin_amdgcn_s_barrier();  // stage(j) landed & visible block-wide
    SCHEDB;

    f32x4 acc[8];
#pragma unroll
    for (int mf = 0; mf < 8; ++mf) acc[mf] = f32x4{0.f, 0.f, 0.f, 0.f};

#pragma unroll
    for (int kw = 0; kw < 3; ++kw)
#pragma unroll
      for (int ks = 0; ks < 2; ++ks) {
        const int col = ol + kw;
        const int sb8 = (ks << 2) | kg;
        bf16x8 a[4];
#pragma unroll
        for (int u = 0; u < 3; ++u) {
          int slot = sb8 ^ ((2 * u + col) & 7);
          a[u] = *reinterpret_cast<const bf16x8*>(smem + boff + (u * 18 + col) * 128 +
                                                  slot * 16);
        }
#pragma unroll
        for (int mf = 0; mf < 8; ++mf) {
          if (mf < 7) {
            int rr = mf + 3;
            int slot = sb8 ^ ((2 * rr + col) & 7);
            a[(mf + 3) & 3] = *reinterpret_cast<const bf16x8*>(
                smem + boff + (rr * 18 + col) * 128 + slot * 16);
          }
          acc[mf] = __builtin_amdgcn_mfma_f32_16x16x32_bf16(a[mf & 3], wf[0][kw][ks],
                                                            acc[mf], 0, 0, 0);
          acc[mf] = __builtin_amdgcn_mfma_f32_16x16x32_bf16(a[(mf + 1) & 3], wf[1][kw][ks],
                                                            acc[mf], 0, 0, 0);
          acc[mf] = __builtin_amdgcn_mfma_f32_16x16x32_bf16(a[(mf + 2) & 3], wf[2][kw][ks],
                                                            acc[mf], 0, 0, 0);
        }
      }

    // ---- epilogue: bn2 + residual + relu -> direct NCHW f32x4 stores ----
    if constexpr (RESID) {
#pragma unroll
      for (int mf = 0; mf < 8; ++mf) {
        int h = th0 + mf, hp = h + 1;
        f32x4 vv;
#pragma unroll
        for (int rg = 0; rg < 4; ++rg) {
          int wq = kg * 4 + rg, wp = tw0 + wq + 1;
          int key = (2 * hp + wp) & 7;
          u16 bv = *reinterpret_cast<const u16*>(
              smem + boff + BUFB + (mf * 16 + wq) * 128 + (((o >> 3) ^ key) * 16) +
              (o & 7) * 2);
          vv[rg] = fmaxf(acc[mf][rg] * inv + bias + b2f(bv), 0.f);
        }
        *reinterpret_cast<f32x4*>(out + (((b * 64 + o) * NH + h) * NW + tw0 + kg * 4)) =
            vv;
      }
    } else {
#pragma unroll
      for (int half = 0; half < 2; ++half) {
        f32x4 xr[4];
#pragma unroll
        for (int m = 0; m < 4; ++m) {
          int h = th0 + half * 4 + m;
          xr[m] = *reinterpret_cast<const f32x4*>(
              x + (((b * 64 + o) * NH + h) * NW + tw0 + kg * 4));
        }
#pragma unroll
        for (int m = 0; m < 4; ++m) {
          int mf = half * 4 + m;
          int h = th0 + mf;
          f32x4 vv;
#pragma unroll
          for (int rg = 0; rg < 4; ++rg)
            vv[rg] = fmaxf(acc[mf][rg] * inv + bias + xr[m][rg], 0.f);
          *reinterpret_cast<f32x4*>(out + (((b * 64 + o) * NH + h) * NW + tw0 + kg * 4)) =
              vv;
        }
      }
    }

    if (j + 1 < n) {
      SCHEDB;
      __builtin_amdgcn_s_barrier();  // buf reads (A + res) done -> restageable
      SCHEDB;
      if (j + 2 < n) {
        stage(sb + ((j + 2) << 9), boff);
        gateS();  // stage(j+1) done; stage(j+2) stays outstanding
      } else {
        WAITVM(0);  // stage(j+1) done (no further stages)
      }
      SCHEDB;
    }
  }
}

// ---------------------------------------------------------------------------
extern "C" void kernel_launch(void* const* d_in, const int* in_sizes, int n_in,
                              void* d_out, int out_size, void* d_ws, size_t ws_size,
                              hipStream_t stream) {
  const float* x = (const float*)d_in[0];
  const float* w1 = (const float*)d_in[1];
  const float* w2 = (const float*)d_in[2];
  const float* alpha = (const float*)d_in[3];
  const float* g1 = (const float*)d_in[4];
  const float* b1 = (const float*)d_in[5];
  const float* m1 = (const float*)d_in[6];
  const float* v1 = (const float*)d_in[7];
  const float* g2 = (const float*)d_in[8];
  const float* b2 = (const float*)d_in[9];
  const float* m2 = (const float*)d_in[10];
  const float* v2 = (const float*)d_in[11];
  float* out = (float*)d_out;

  char* ws = (char*)d_ws;
  u16* weff1 = (u16*)ws;                 // 73728 B
  u16* weff2 = (u16*)(ws + 73728);       // 73728 B
  float* bnc = (float*)(ws + 147456);    // 1024 B
  u16* y1pad = (u16*)(ws + 148480);      // 53231616 B
  const size_t PADB = 53231616ull;       // 32*114*114*64*2
  bool big = ws_size >= 148480ull + 2ull * PADB;
  // big ws: xpad in ws (stays live through P1 -> bf16 residual source).
  // small ws: xpad in d_out (dead before P1 writes) -> fp32-x residual.
  u16* xpad = big ? (u16*)(ws + 148480 + PADB) : (u16*)d_out;

  border_zero<<<904, 256, 0, stream>>>(xpad, y1pad);
  transform_kernel<<<32 * NH, 256, 0, stream>>>(x, xpad);
  prep_kernel<<<144, 256, 0, stream>>>(w1, w2, alpha, g1, b1, m1, v1,
                                       g2, b2, m2, v2, weff1, weff2, bnc);
  conv_p0_kernel<<<512, 256, 0, stream>>>(xpad, weff1, bnc, y1pad);
  if (big)
    conv_p1_kernel<1><<<512, 256, 0, stream>>>(y1pad, x, xpad, weff2, bnc, out);
  else
    conv_p1_kernel<0><<<512, 256, 0, stream>>>(y1pad, x, nullptr, weff2, bnc, out);
}